// Round 3
// 1609.537 us; speedup vs baseline: 1.3242x; 1.3242x over previous
//
#include <hip/hip_runtime.h>

#define N_ 32
#define C_ 64
#define T_ 64
#define V_ 204
#define H_ 3
#define TV_ (T_ * V_)          // 13056
#define CTV_ (C_ * TV_)        // 835584
#define VG_ (V_ / 4)           // 51
#define NH_ (N_ * H_)          // 96
#define EPS_ 1e-5f
#define ATT_SC_ (1.0f / 3264.0f)
#define STV_ (H_ * TV_)        // 39168
#define KP_ 224                // padded K (v) for MFMA
#define UP_ 208                // padded u rows of A

typedef __bf16 bf16x8 __attribute__((ext_vector_type(8)));
typedef float  f32x4  __attribute__((ext_vector_type(4)));

// ---------------------------------------------------------------------------
// K0: Apad[u][v] = bf16(A[u][v]) zero-padded to 208x224
// ---------------------------------------------------------------------------
__global__ __launch_bounds__(224) void k0_cvtA(
    const float* __restrict__ A, __bf16* __restrict__ Apad)
{
    const int u = blockIdx.x;       // 0..207
    const int v = threadIdx.x;      // 0..223
    float val = (u < V_ && v < V_) ? A[u * V_ + v] : 0.f;
    Apad[u * KP_ + v] = (__bf16)val;
}

// ---------------------------------------------------------------------------
// K1a: h[r][v] = bf16(bias[c] + sum_a W[c,a] x[n,a,t,v]), r=(n,c,t), row KP_
// ---------------------------------------------------------------------------
__global__ __launch_bounds__(256) void k1a_h(
    const float* __restrict__ x, const float* __restrict__ W,
    const float* __restrict__ bias, __bf16* __restrict__ h)
{
    const int t = blockIdx.x, n = blockIdx.y;
    const int v = threadIdx.x;
    if (v >= KP_) return;
    __bf16* hp = h + ((size_t)n * 4096 + t) * KP_ + v;   // + c*64*KP_ per row
    if (v >= V_) {
#pragma unroll 1
        for (int c = 0; c < C_; ++c) hp[(size_t)c * 64 * KP_] = (__bf16)0.f;
        return;
    }
    float xc[C_];
    const float* xp = x + (size_t)n * CTV_ + (size_t)t * V_ + v;
#pragma unroll
    for (int a = 0; a < C_; ++a) xc[a] = xp[(size_t)a * TV_];
#pragma unroll 1
    for (int c = 0; c < C_; ++c) {
        float acc = bias[c];
#pragma unroll
        for (int a = 0; a < C_; ++a) acc = fmaf(W[c * C_ + a], xc[a], acc);
        hp[(size_t)c * 64 * KP_] = (__bf16)acc;
    }
}

// ---------------------------------------------------------------------------
// K1b: G[r,u] = sum_v h[r,v] * Apad[u,v]  (MFMA 16x16x32 bf16)
//      g = relu(s*G + sh + x) fused epilogue. 2048 blocks x 256 thr, no LDS.
// ---------------------------------------------------------------------------
__global__ __launch_bounds__(256) void k1b_mfma(
    const __bf16* __restrict__ h, const __bf16* __restrict__ Apad,
    const float* __restrict__ x,
    const float* __restrict__ bng, const float* __restrict__ bnb,
    const float* __restrict__ bnm, const float* __restrict__ bnv,
    float* __restrict__ g_out)
{
    const int wave = threadIdx.x >> 6;
    const int lane = threadIdx.x & 63;
    const int l16  = lane & 15;
    const int quad = lane >> 4;

    const __bf16* hA = h + (size_t)(blockIdx.x * 64 + wave * 16 + l16) * KP_ + quad * 8;
    const __bf16* Bp = Apad + (size_t)l16 * KP_ + quad * 8;

    f32x4 acc[13];
#pragma unroll
    for (int j = 0; j < 13; ++j) acc[j] = (f32x4){0.f, 0.f, 0.f, 0.f};

#pragma unroll 1
    for (int kc = 0; kc < 7; ++kc) {
        const bf16x8 af = *(const bf16x8*)(hA + kc * 32);
        bf16x8 bf[13];
#pragma unroll
        for (int j = 0; j < 13; ++j)
            bf[j] = *(const bf16x8*)(Bp + (size_t)j * 16 * KP_ + kc * 32);
#pragma unroll
        for (int j = 0; j < 13; ++j)
            acc[j] = __builtin_amdgcn_mfma_f32_16x16x32_bf16(af, bf[j], acc[j], 0, 0, 0);
    }

    // epilogue: block covers exactly one (n,c), t = 0..63
    const int c = blockIdx.x & 63;
    const float s1 = bng[c] * rsqrtf(bnv[c] + EPS_);
    const float sh = bnb[c] - bnm[c] * s1;
    const int rbase = blockIdx.x * 64 + wave * 16 + quad * 4;

#pragma unroll 1
    for (int j = 0; j < 13; ++j) {
        const int u = j * 16 + l16;
        if (u < V_) {
#pragma unroll
            for (int i = 0; i < 4; ++i) {
                const size_t r = (size_t)(rbase + i);
                const float val = acc[j][i] * s1 + sh + x[r * V_ + u];
                g_out[r * V_ + u] = fmaxf(val, 0.f);
            }
        }
    }
}

// ---------------------------------------------------------------------------
// K2: qk[n, j, t, v] = qkv_w @ (g + pe) + qkv_b
// ---------------------------------------------------------------------------
__global__ __launch_bounds__(256) void k2_qkv(
    const float* __restrict__ g_ws, const float* __restrict__ pe,
    const float* __restrict__ qw, const float* __restrict__ qb,
    float* __restrict__ qk_ws)
{
    const int t = blockIdx.x, n = blockIdx.y;
    const int v = threadIdx.x;
    if (v >= V_) return;
    float xc[C_];
    const float* gp = g_ws + (size_t)n * CTV_ + (size_t)t * V_ + v;
    const float* pp = pe + (size_t)t * V_ + v;
#pragma unroll
    for (int a = 0; a < C_; ++a) xc[a] = gp[(size_t)a * TV_] + pp[(size_t)a * TV_];
    float* op = qk_ws + (size_t)n * 96 * TV_ + (size_t)t * V_ + v;
#pragma unroll 1
    for (int j = 0; j < 96; ++j) {
        float acc = qb[j];
#pragma unroll
        for (int a = 0; a < C_; ++a) acc = fmaf(qw[j * C_ + a], xc[a], acc);
        op[(size_t)j * TV_] = acc;
    }
}

// ---------------------------------------------------------------------------
// K3a: att partials; K3b: finalize
// ---------------------------------------------------------------------------
__global__ __launch_bounds__(64) void k3_att_part(
    const float* __restrict__ qk_ws, float* __restrict__ part)
{
    const int qcg = blockIdx.x;
    const int n = blockIdx.y;
    const int h  = blockIdx.z >> 2;
    const int wv = blockIdx.z & 3;
    const int q = threadIdx.x;
    float acc[16];
#pragma unroll
    for (int i = 0; i < 16; ++i) acc[i] = 0.f;

#pragma unroll 1
    for (int qc2 = 0; qc2 < 2; ++qc2) {
        const int qc = qcg * 2 + qc2;
        const float* Qp = qk_ws + (size_t)(n * 96 + h * 16 + qc) * TV_;
        const float* Kp = qk_ws + (size_t)(n * 96 + 48 + h * 16 + qc) * TV_;
#pragma unroll 1
        for (int vc = 0; vc < 3; ++vc) {
            const int v0 = vc * 68;
            float kr[68];
            const float* kp = Kp + (size_t)q * V_ + v0;
#pragma unroll
            for (int m = 0; m < 17; ++m) {
                float4 f = *(const float4*)(kp + m * 4);
                kr[m * 4 + 0] = f.x; kr[m * 4 + 1] = f.y;
                kr[m * 4 + 2] = f.z; kr[m * 4 + 3] = f.w;
            }
#pragma unroll 1
            for (int ti = 0; ti < 16; ++ti) {
                const int tt = wv * 16 + ti;
                const float* qp = Qp + (size_t)tt * V_ + v0;
                float a = acc[ti];
#pragma unroll
                for (int vv = 0; vv < 68; ++vv) a = fmaf(qp[vv], kr[vv], a);
                acc[ti] = a;
            }
        }
    }
    float* pp = part + ((size_t)qcg * NH_ + (size_t)(n * H_ + h)) * 4096;
#pragma unroll
    for (int ti = 0; ti < 16; ++ti) pp[(wv * 16 + ti) * 64 + q] = acc[ti];
}

__global__ __launch_bounds__(256) void k3_att_fin(
    const float* __restrict__ part, const float* __restrict__ alphas,
    const float* __restrict__ att1s, float* __restrict__ att_ws)
{
    const int i = blockIdx.x * 256 + threadIdx.x;
    float s = 0.f;
#pragma unroll
    for (int p = 0; p < 8; ++p) s += part[(size_t)p * NH_ * 4096 + i];
    const int nh = i >> 12;
    const int h  = nh % H_;
    const int tq = i & 4095;
    att_ws[i] = tanhf(s * ATT_SC_) * alphas[h] + att1s[h * 4096 + tq];
}

// ---------------------------------------------------------------------------
// K4a: P[n',o,s,t,v] = sum_c on_w[o, s*64+c] * g[n,c,t,v]
//      v2: 4-way o-split (gridDim.z), on_w slice staged in LDS (float4),
//      unroll-2 o-loop
// ---------------------------------------------------------------------------
__global__ __launch_bounds__(256) void k4a_pw(
    const float* __restrict__ g_chunk,
    const float* __restrict__ onw,
    float* __restrict__ P)
{
    __shared__ float ws[16 * 192];
    const int t = blockIdx.x, np = blockIdx.y, og = blockIdx.z;
    const int o0 = og * 16;
    const int tid = threadIdx.x;

    // stage on_w[o0 .. o0+16) rows (16 x 192 = 3072 floats = 768 float4)
    {
        const float4* src = (const float4*)(onw + (size_t)o0 * 192);
        float4* dst = (float4*)ws;
#pragma unroll
        for (int i = 0; i < 3; ++i)
            dst[tid + i * 256] = src[tid + i * 256];
    }
    __syncthreads();

    const int v = tid;
    if (v >= V_) return;

    float gc[C_];
    const float* gp = g_chunk + (size_t)np * CTV_ + (size_t)t * V_ + v;
#pragma unroll
    for (int c = 0; c < C_; ++c) gc[c] = gp[(size_t)c * TV_];

    float* Pp = P + (size_t)np * 64 * STV_ + (size_t)t * V_ + v;
#pragma unroll 2
    for (int oo = 0; oo < 16; ++oo) {
        const int o = o0 + oo;
        float acc0 = 0.f, acc1 = 0.f, acc2 = 0.f;
        const float* wr = ws + oo * 192;
#pragma unroll
        for (int c = 0; c < C_; ++c) {
            acc0 = fmaf(wr[c],       gc[c], acc0);
            acc1 = fmaf(wr[64 + c],  gc[c], acc1);
            acc2 = fmaf(wr[128 + c], gc[c], acc2);
        }
        float* po = Pp + (size_t)o * STV_;
        po[0]               = acc0;
        po[(size_t)TV_]     = acc1;
        po[(size_t)2 * TV_] = acc2;
    }
}

// ---------------------------------------------------------------------------
// K4b: z[n,o,q,v] = sum_st att[n,s,t,q] * P[n',o,st,v]; fused epilogue
// ---------------------------------------------------------------------------
__global__ __launch_bounds__(256) void k4b_apply(
    const float* __restrict__ P,
    const float* __restrict__ att_chunk,
    const float* __restrict__ g_chunk,
    const float* __restrict__ onb,
    const float* __restrict__ bng, const float* __restrict__ bnb,
    const float* __restrict__ bnm, const float* __restrict__ bnv,
    float* __restrict__ out_chunk)
{
    __shared__ float att_s[192 * 64];
    const int o = blockIdx.x, np = blockIdx.y;
    const int tid = threadIdx.x;

    {
        const float4* src = (const float4*)(att_chunk + (size_t)np * (H_ * 4096));
        float4* dst = (float4*)att_s;
#pragma unroll
        for (int i = 0; i < 12; ++i) dst[tid + i * 256] = src[tid + i * 256];
    }
    __syncthreads();

    if (tid < 204) {
        const int vg = tid % 51, qg = tid / 51;
        const int v0 = vg * 4, q0 = qg * 16;

        float4 acc[16];
#pragma unroll
        for (int i = 0; i < 16; ++i) acc[i] = make_float4(0.f, 0.f, 0.f, 0.f);

        const float* Pp = P + (size_t)(np * 64 + o) * STV_ + v0;
#pragma unroll 2
        for (int st = 0; st < 192; ++st) {
            const float4 p = *(const float4*)(Pp + (size_t)st * V_);
            const float* ar = att_s + st * 64 + q0;
#pragma unroll
            for (int j = 0; j < 4; ++j) {
                const float4 a4 = *(const float4*)(ar + j * 4);
                acc[j * 4 + 0].x = fmaf(a4.x, p.x, acc[j * 4 + 0].x);
                acc[j * 4 + 0].y = fmaf(a4.x, p.y, acc[j * 4 + 0].y);
                acc[j * 4 + 0].z = fmaf(a4.x, p.z, acc[j * 4 + 0].z);
                acc[j * 4 + 0].w = fmaf(a4.x, p.w, acc[j * 4 + 0].w);
                acc[j * 4 + 1].x = fmaf(a4.y, p.x, acc[j * 4 + 1].x);
                acc[j * 4 + 1].y = fmaf(a4.y, p.y, acc[j * 4 + 1].y);
                acc[j * 4 + 1].z = fmaf(a4.y, p.z, acc[j * 4 + 1].z);
                acc[j * 4 + 1].w = fmaf(a4.y, p.w, acc[j * 4 + 1].w);
                acc[j * 4 + 2].x = fmaf(a4.z, p.x, acc[j * 4 + 2].x);
                acc[j * 4 + 2].y = fmaf(a4.z, p.y, acc[j * 4 + 2].y);
                acc[j * 4 + 2].z = fmaf(a4.z, p.z, acc[j * 4 + 2].z);
                acc[j * 4 + 2].w = fmaf(a4.z, p.w, acc[j * 4 + 2].w);
                acc[j * 4 + 3].x = fmaf(a4.w, p.x, acc[j * 4 + 3].x);
                acc[j * 4 + 3].y = fmaf(a4.w, p.y, acc[j * 4 + 3].y);
                acc[j * 4 + 3].z = fmaf(a4.w, p.z, acc[j * 4 + 3].z);
                acc[j * 4 + 3].w = fmaf(a4.w, p.w, acc[j * 4 + 3].w);
            }
        }

        const float s1 = bng[o] * rsqrtf(bnv[o] + EPS_);
        const float sh = onb[o] * s1 + bnb[o] - bnm[o] * s1;
        const float* gp = g_chunk + (size_t)np * CTV_ + (size_t)o * TV_ + v0;
        float* zp = out_chunk + (size_t)np * CTV_ + (size_t)o * TV_ + v0;
#pragma unroll 1
        for (int i = 0; i < 16; ++i) {
            const int q = q0 + i;
            const float4 g4 = *(const float4*)(gp + (size_t)q * V_);
            float4 val;
            val.x = acc[i].x * s1 + sh + g4.x;
            val.y = acc[i].y * s1 + sh + g4.y;
            val.z = acc[i].z * s1 + sh + g4.z;
            val.w = acc[i].w * s1 + sh + g4.w;
            val.x = (val.x > 0.f) ? val.x : 0.1f * val.x;
            val.y = (val.y > 0.f) ? val.y : 0.1f * val.y;
            val.z = (val.z > 0.f) ? val.z : 0.1f * val.z;
            val.w = (val.w > 0.f) ? val.w : 0.1f * val.w;
            *(float4*)(zp + (size_t)q * V_) = val;
        }
    }
}

// ---------------------------------------------------------------------------
// K5: out = leaky(bn(ff_w @ y3 + ff_b) + g), in-place on d_out
// ---------------------------------------------------------------------------
__global__ __launch_bounds__(256) void k5_ff(
    const float* __restrict__ g_ws, const float* __restrict__ fw, const float* __restrict__ fb,
    const float* __restrict__ bng, const float* __restrict__ bnb,
    const float* __restrict__ bnm, const float* __restrict__ bnv,
    float* __restrict__ io)
{
    const int t = blockIdx.x, n = blockIdx.y;
    const int v = threadIdx.x;
    if (v >= V_) return;
    float yc[C_];
    float* bp = io + (size_t)n * CTV_ + (size_t)t * V_ + v;
#pragma unroll
    for (int a = 0; a < C_; ++a) yc[a] = bp[(size_t)a * TV_];
    const float* gp = g_ws + (size_t)n * CTV_ + (size_t)t * V_ + v;
#pragma unroll 1
    for (int o = 0; o < C_; ++o) {
        float acc = fb[o];
#pragma unroll
        for (int a = 0; a < C_; ++a) acc = fmaf(fw[o * C_ + a], yc[a], acc);
        const float s1 = bng[o] * rsqrtf(bnv[o] + EPS_);
        float val = acc * s1 + (bnb[o] - bnm[o] * s1) + gp[(size_t)o * TV_];
        bp[(size_t)o * TV_] = (val > 0.f) ? val : 0.1f * val;
    }
}

// ---------------------------------------------------------------------------
extern "C" void kernel_launch(void* const* d_in, const int* in_sizes, int n_in,
                              void* d_out, int out_size, void* d_ws, size_t ws_size,
                              hipStream_t stream)
{
    (void)in_sizes; (void)n_in; (void)out_size; (void)ws_size;
    const float* x      = (const float*)d_in[0];
    const float* A      = (const float*)d_in[1];
    const float* gcn_w  = (const float*)d_in[2];
    const float* gcn_b  = (const float*)d_in[3];
    const float* gcn_g  = (const float*)d_in[4];
    const float* gcn_bb = (const float*)d_in[5];
    const float* gcn_m  = (const float*)d_in[6];
    const float* gcn_v  = (const float*)d_in[7];
    const float* pe     = (const float*)d_in[8];
    const float* qkv_w  = (const float*)d_in[9];
    const float* qkv_b  = (const float*)d_in[10];
    const float* alphas = (const float*)d_in[11];
    const float* att1s  = (const float*)d_in[12];
    const float* on_w   = (const float*)d_in[13];
    const float* on_b   = (const float*)d_in[14];
    const float* on_g   = (const float*)d_in[15];
    const float* on_bb  = (const float*)d_in[16];
    const float* on_m   = (const float*)d_in[17];
    const float* on_v   = (const float*)d_in[18];
    const float* ff_w   = (const float*)d_in[19];
    const float* ff_b   = (const float*)d_in[20];
    const float* ff_g   = (const float*)d_in[21];
    const float* ff_bb  = (const float*)d_in[22];
    const float* ff_m   = (const float*)d_in[23];
    const float* ff_v   = (const float*)d_in[24];
    float* out = (float*)d_out;

    float* g_ws    = (float*)d_ws;                         // 26,738,688 f
    float* qk_ws   = g_ws   + (size_t)N_ * CTV_;           // 40,108,032 f
    float* part_ws = qk_ws  + (size_t)N_ * 96 * TV_;       //  3,145,728 f
    float* att_ws  = part_ws + (size_t)8 * NH_ * 4096;     //    393,216 f
    float* P_ws    = qk_ws;                                // alias (qk dead after k3)
    __bf16* h_ws   = (__bf16*)qk_ws;                       // alias (dead before k2 writes)
    __bf16* Apad   = (__bf16*)part_ws;                     // alias (dead before k3a writes)

    k0_cvtA<<<dim3(UP_), 224, 0, stream>>>(A, Apad);
    k1a_h  <<<dim3(T_, N_), 256, 0, stream>>>(x, gcn_w, gcn_b, h_ws);
    k1b_mfma<<<dim3(2048), 256, 0, stream>>>(h_ws, Apad, x,
                                             gcn_g, gcn_bb, gcn_m, gcn_v, g_ws);
    k2_qkv<<<dim3(T_, N_), 256, 0, stream>>>(g_ws, pe, qkv_w, qkv_b, qk_ws);
    k3_att_part<<<dim3(8, N_, 12), 64, 0, stream>>>(qk_ws, part_ws);
    k3_att_fin<<<dim3((NH_ * 4096) / 256), 256, 0, stream>>>(part_ws, alphas, att1s, att_ws);

    for (int chunk = 0; chunk < 2; ++chunk) {
        const int nb = chunk * 16;
        k4a_pw<<<dim3(T_, 16, 4), 256, 0, stream>>>(g_ws + (size_t)nb * CTV_, on_w, P_ws);
        k4b_apply<<<dim3(64, 16), 256, 0, stream>>>(
            P_ws, att_ws + (size_t)nb * H_ * 4096, g_ws + (size_t)nb * CTV_,
            on_b, on_g, on_bb, on_m, on_v, out + (size_t)nb * CTV_);
    }
    k5_ff<<<dim3(T_, N_), 256, 0, stream>>>(g_ws, ff_w, ff_b, ff_g, ff_bb, ff_m, ff_v, out);
}

// Round 4
// 1524.552 us; speedup vs baseline: 1.3980x; 1.0557x over previous
//
#include <hip/hip_runtime.h>

#define N_ 32
#define C_ 64
#define T_ 64
#define V_ 204
#define H_ 3
#define TV_ (T_ * V_)          // 13056
#define CTV_ (C_ * TV_)        // 835584
#define VG_ (V_ / 4)           // 51
#define NH_ (N_ * H_)          // 96
#define EPS_ 1e-5f
#define ATT_SC_ (1.0f / 3264.0f)
#define STV_ (H_ * TV_)        // 39168
#define KP_ 224                // padded K (v) for MFMA
#define UP_ 208                // padded u rows of A

typedef __bf16 bf16x8 __attribute__((ext_vector_type(8)));
typedef float  f32x4  __attribute__((ext_vector_type(4)));

// ---------------------------------------------------------------------------
// K0: Apad[u][v] = bf16(A[u][v]) zero-padded to 208x224
// ---------------------------------------------------------------------------
__global__ __launch_bounds__(224) void k0_cvtA(
    const float* __restrict__ A, __bf16* __restrict__ Apad)
{
    const int u = blockIdx.x;       // 0..207
    const int v = threadIdx.x;      // 0..223
    float val = (u < V_ && v < V_) ? A[u * V_ + v] : 0.f;
    Apad[u * KP_ + v] = (__bf16)val;
}

// ---------------------------------------------------------------------------
// K1a: h[r][v] = bf16(bias[c] + sum_a W[c,a] x[n,a,t,v]), r=(n,c,t), row KP_
//      v2: W staged in LDS (16 KB), unroll-2 c-loop
// ---------------------------------------------------------------------------
__global__ __launch_bounds__(256) void k1a_h(
    const float* __restrict__ x, const float* __restrict__ W,
    const float* __restrict__ bias, __bf16* __restrict__ h)
{
    __shared__ float ws[C_ * C_];            // 16 KB
    const int t = blockIdx.x, n = blockIdx.y;
    const int tid = threadIdx.x;
    {
        const float4* src = (const float4*)W;
        float4* dst = (float4*)ws;
#pragma unroll
        for (int i = 0; i < 4; ++i) dst[tid + i * 256] = src[tid + i * 256];
    }
    __syncthreads();

    const int v = tid;
    if (v >= KP_) return;
    __bf16* hp = h + ((size_t)n * 4096 + t) * KP_ + v;   // + c*64*KP_ per row
    if (v >= V_) {
#pragma unroll 1
        for (int c = 0; c < C_; ++c) hp[(size_t)c * 64 * KP_] = (__bf16)0.f;
        return;
    }
    float xc[C_];
    const float* xp = x + (size_t)n * CTV_ + (size_t)t * V_ + v;
#pragma unroll
    for (int a = 0; a < C_; ++a) xc[a] = xp[(size_t)a * TV_];
#pragma unroll 2
    for (int c = 0; c < C_; ++c) {
        float acc = bias[c];
        const float* wr = ws + c * C_;
#pragma unroll
        for (int a = 0; a < C_; ++a) acc = fmaf(wr[a], xc[a], acc);
        hp[(size_t)c * 64 * KP_] = (__bf16)acc;
    }
}

// ---------------------------------------------------------------------------
// K1b: G[r,u] = sum_v h[r,v] * Apad[u,v]  (MFMA 16x16x32 bf16)
//      g = relu(s*G + sh + x) fused epilogue. 2048 blocks x 256 thr, no LDS.
// ---------------------------------------------------------------------------
__global__ __launch_bounds__(256) void k1b_mfma(
    const __bf16* __restrict__ h, const __bf16* __restrict__ Apad,
    const float* __restrict__ x,
    const float* __restrict__ bng, const float* __restrict__ bnb,
    const float* __restrict__ bnm, const float* __restrict__ bnv,
    float* __restrict__ g_out)
{
    const int wave = threadIdx.x >> 6;
    const int lane = threadIdx.x & 63;
    const int l16  = lane & 15;
    const int quad = lane >> 4;

    const __bf16* hA = h + (size_t)(blockIdx.x * 64 + wave * 16 + l16) * KP_ + quad * 8;
    const __bf16* Bp = Apad + (size_t)l16 * KP_ + quad * 8;

    f32x4 acc[13];
#pragma unroll
    for (int j = 0; j < 13; ++j) acc[j] = (f32x4){0.f, 0.f, 0.f, 0.f};

#pragma unroll 1
    for (int kc = 0; kc < 7; ++kc) {
        const bf16x8 af = *(const bf16x8*)(hA + kc * 32);
        bf16x8 bf[13];
#pragma unroll
        for (int j = 0; j < 13; ++j)
            bf[j] = *(const bf16x8*)(Bp + (size_t)j * 16 * KP_ + kc * 32);
#pragma unroll
        for (int j = 0; j < 13; ++j)
            acc[j] = __builtin_amdgcn_mfma_f32_16x16x32_bf16(af, bf[j], acc[j], 0, 0, 0);
    }

    // epilogue: block covers exactly one (n,c), t = 0..63
    const int c = blockIdx.x & 63;
    const float s1 = bng[c] * rsqrtf(bnv[c] + EPS_);
    const float sh = bnb[c] - bnm[c] * s1;
    const int rbase = blockIdx.x * 64 + wave * 16 + quad * 4;

#pragma unroll 1
    for (int j = 0; j < 13; ++j) {
        const int u = j * 16 + l16;
        if (u < V_) {
#pragma unroll
            for (int i = 0; i < 4; ++i) {
                const size_t r = (size_t)(rbase + i);
                const float val = acc[j][i] * s1 + sh + x[r * V_ + u];
                g_out[r * V_ + u] = fmaxf(val, 0.f);
            }
        }
    }
}

// ---------------------------------------------------------------------------
// K2: qk[n, j, t, v] = qkv_w @ (g + pe) + qkv_b
//     v2: 4-way j-split (gridDim.z), qkv_w slice in LDS (6 KB), unroll-2
// ---------------------------------------------------------------------------
__global__ __launch_bounds__(256) void k2_qkv(
    const float* __restrict__ g_ws, const float* __restrict__ pe,
    const float* __restrict__ qw, const float* __restrict__ qb,
    float* __restrict__ qk_ws)
{
    __shared__ float ws[24 * C_];            // 6 KB
    const int t = blockIdx.x, n = blockIdx.y, jg = blockIdx.z;
    const int j0 = jg * 24;
    const int tid = threadIdx.x;
    {
        const float4* src = (const float4*)(qw + (size_t)j0 * C_);
        float4* dst = (float4*)ws;
#pragma unroll 1
        for (int i = tid; i < 384; i += 256) dst[i] = src[i];
    }
    __syncthreads();

    const int v = tid;
    if (v >= V_) return;
    float xc[C_];
    const float* gp = g_ws + (size_t)n * CTV_ + (size_t)t * V_ + v;
    const float* pp = pe + (size_t)t * V_ + v;
#pragma unroll
    for (int a = 0; a < C_; ++a) xc[a] = gp[(size_t)a * TV_] + pp[(size_t)a * TV_];
    float* op = qk_ws + (size_t)n * 96 * TV_ + (size_t)t * V_ + v;
#pragma unroll 2
    for (int jj = 0; jj < 24; ++jj) {
        const int j = j0 + jj;
        float acc = qb[j];
        const float* wr = ws + jj * C_;
#pragma unroll
        for (int a = 0; a < C_; ++a) acc = fmaf(wr[a], xc[a], acc);
        op[(size_t)j * TV_] = acc;
    }
}

// ---------------------------------------------------------------------------
// K3a: att partials; K3b: finalize
// ---------------------------------------------------------------------------
__global__ __launch_bounds__(64) void k3_att_part(
    const float* __restrict__ qk_ws, float* __restrict__ part)
{
    const int qcg = blockIdx.x;
    const int n = blockIdx.y;
    const int h  = blockIdx.z >> 2;
    const int wv = blockIdx.z & 3;
    const int q = threadIdx.x;
    float acc[16];
#pragma unroll
    for (int i = 0; i < 16; ++i) acc[i] = 0.f;

#pragma unroll 1
    for (int qc2 = 0; qc2 < 2; ++qc2) {
        const int qc = qcg * 2 + qc2;
        const float* Qp = qk_ws + (size_t)(n * 96 + h * 16 + qc) * TV_;
        const float* Kp = qk_ws + (size_t)(n * 96 + 48 + h * 16 + qc) * TV_;
#pragma unroll 1
        for (int vc = 0; vc < 3; ++vc) {
            const int v0 = vc * 68;
            float kr[68];
            const float* kp = Kp + (size_t)q * V_ + v0;
#pragma unroll
            for (int m = 0; m < 17; ++m) {
                float4 f = *(const float4*)(kp + m * 4);
                kr[m * 4 + 0] = f.x; kr[m * 4 + 1] = f.y;
                kr[m * 4 + 2] = f.z; kr[m * 4 + 3] = f.w;
            }
#pragma unroll 1
            for (int ti = 0; ti < 16; ++ti) {
                const int tt = wv * 16 + ti;
                const float* qp = Qp + (size_t)tt * V_ + v0;
                float a = acc[ti];
#pragma unroll
                for (int vv = 0; vv < 68; ++vv) a = fmaf(qp[vv], kr[vv], a);
                acc[ti] = a;
            }
        }
    }
    float* pp = part + ((size_t)qcg * NH_ + (size_t)(n * H_ + h)) * 4096;
#pragma unroll
    for (int ti = 0; ti < 16; ++ti) pp[(wv * 16 + ti) * 64 + q] = acc[ti];
}

__global__ __launch_bounds__(256) void k3_att_fin(
    const float* __restrict__ part, const float* __restrict__ alphas,
    const float* __restrict__ att1s, float* __restrict__ att_ws)
{
    const int i = blockIdx.x * 256 + threadIdx.x;
    float s = 0.f;
#pragma unroll
    for (int p = 0; p < 8; ++p) s += part[(size_t)p * NH_ * 4096 + i];
    const int nh = i >> 12;
    const int h  = nh % H_;
    const int tq = i & 4095;
    att_ws[i] = tanhf(s * ATT_SC_) * alphas[h] + att1s[h * 4096 + tq];
}

// ---------------------------------------------------------------------------
// K4a: P[n',o,s,t,v] = sum_c on_w[o, s*64+c] * g[n,c,t,v]
//      v2: 4-way o-split (gridDim.z), on_w slice staged in LDS (float4),
//      unroll-2 o-loop
// ---------------------------------------------------------------------------
__global__ __launch_bounds__(256) void k4a_pw(
    const float* __restrict__ g_chunk,
    const float* __restrict__ onw,
    float* __restrict__ P)
{
    __shared__ float ws[16 * 192];
    const int t = blockIdx.x, np = blockIdx.y, og = blockIdx.z;
    const int o0 = og * 16;
    const int tid = threadIdx.x;

    // stage on_w[o0 .. o0+16) rows (16 x 192 = 3072 floats = 768 float4)
    {
        const float4* src = (const float4*)(onw + (size_t)o0 * 192);
        float4* dst = (float4*)ws;
#pragma unroll
        for (int i = 0; i < 3; ++i)
            dst[tid + i * 256] = src[tid + i * 256];
    }
    __syncthreads();

    const int v = tid;
    if (v >= V_) return;

    float gc[C_];
    const float* gp = g_chunk + (size_t)np * CTV_ + (size_t)t * V_ + v;
#pragma unroll
    for (int c = 0; c < C_; ++c) gc[c] = gp[(size_t)c * TV_];

    float* Pp = P + (size_t)np * 64 * STV_ + (size_t)t * V_ + v;
#pragma unroll 2
    for (int oo = 0; oo < 16; ++oo) {
        const int o = o0 + oo;
        float acc0 = 0.f, acc1 = 0.f, acc2 = 0.f;
        const float* wr = ws + oo * 192;
#pragma unroll
        for (int c = 0; c < C_; ++c) {
            acc0 = fmaf(wr[c],       gc[c], acc0);
            acc1 = fmaf(wr[64 + c],  gc[c], acc1);
            acc2 = fmaf(wr[128 + c], gc[c], acc2);
        }
        float* po = Pp + (size_t)o * STV_;
        po[0]               = acc0;
        po[(size_t)TV_]     = acc1;
        po[(size_t)2 * TV_] = acc2;
    }
}

// ---------------------------------------------------------------------------
// K4b: z[n,o,q,v] = sum_st att[n,s,t,q] * P[n',o,st,v]; fused epilogue
// ---------------------------------------------------------------------------
__global__ __launch_bounds__(256) void k4b_apply(
    const float* __restrict__ P,
    const float* __restrict__ att_chunk,
    const float* __restrict__ g_chunk,
    const float* __restrict__ onb,
    const float* __restrict__ bng, const float* __restrict__ bnb,
    const float* __restrict__ bnm, const float* __restrict__ bnv,
    float* __restrict__ out_chunk)
{
    __shared__ float att_s[192 * 64];
    const int o = blockIdx.x, np = blockIdx.y;
    const int tid = threadIdx.x;

    {
        const float4* src = (const float4*)(att_chunk + (size_t)np * (H_ * 4096));
        float4* dst = (float4*)att_s;
#pragma unroll
        for (int i = 0; i < 12; ++i) dst[tid + i * 256] = src[tid + i * 256];
    }
    __syncthreads();

    if (tid < 204) {
        const int vg = tid % 51, qg = tid / 51;
        const int v0 = vg * 4, q0 = qg * 16;

        float4 acc[16];
#pragma unroll
        for (int i = 0; i < 16; ++i) acc[i] = make_float4(0.f, 0.f, 0.f, 0.f);

        const float* Pp = P + (size_t)(np * 64 + o) * STV_ + v0;
#pragma unroll 2
        for (int st = 0; st < 192; ++st) {
            const float4 p = *(const float4*)(Pp + (size_t)st * V_);
            const float* ar = att_s + st * 64 + q0;
#pragma unroll
            for (int j = 0; j < 4; ++j) {
                const float4 a4 = *(const float4*)(ar + j * 4);
                acc[j * 4 + 0].x = fmaf(a4.x, p.x, acc[j * 4 + 0].x);
                acc[j * 4 + 0].y = fmaf(a4.x, p.y, acc[j * 4 + 0].y);
                acc[j * 4 + 0].z = fmaf(a4.x, p.z, acc[j * 4 + 0].z);
                acc[j * 4 + 0].w = fmaf(a4.x, p.w, acc[j * 4 + 0].w);
                acc[j * 4 + 1].x = fmaf(a4.y, p.x, acc[j * 4 + 1].x);
                acc[j * 4 + 1].y = fmaf(a4.y, p.y, acc[j * 4 + 1].y);
                acc[j * 4 + 1].z = fmaf(a4.y, p.z, acc[j * 4 + 1].z);
                acc[j * 4 + 1].w = fmaf(a4.y, p.w, acc[j * 4 + 1].w);
                acc[j * 4 + 2].x = fmaf(a4.z, p.x, acc[j * 4 + 2].x);
                acc[j * 4 + 2].y = fmaf(a4.z, p.y, acc[j * 4 + 2].y);
                acc[j * 4 + 2].z = fmaf(a4.z, p.z, acc[j * 4 + 2].z);
                acc[j * 4 + 2].w = fmaf(a4.z, p.w, acc[j * 4 + 2].w);
                acc[j * 4 + 3].x = fmaf(a4.w, p.x, acc[j * 4 + 3].x);
                acc[j * 4 + 3].y = fmaf(a4.w, p.y, acc[j * 4 + 3].y);
                acc[j * 4 + 3].z = fmaf(a4.w, p.z, acc[j * 4 + 3].z);
                acc[j * 4 + 3].w = fmaf(a4.w, p.w, acc[j * 4 + 3].w);
            }
        }

        const float s1 = bng[o] * rsqrtf(bnv[o] + EPS_);
        const float sh = onb[o] * s1 + bnb[o] - bnm[o] * s1;
        const float* gp = g_chunk + (size_t)np * CTV_ + (size_t)o * TV_ + v0;
        float* zp = out_chunk + (size_t)np * CTV_ + (size_t)o * TV_ + v0;
#pragma unroll 1
        for (int i = 0; i < 16; ++i) {
            const int q = q0 + i;
            const float4 g4 = *(const float4*)(gp + (size_t)q * V_);
            float4 val;
            val.x = acc[i].x * s1 + sh + g4.x;
            val.y = acc[i].y * s1 + sh + g4.y;
            val.z = acc[i].z * s1 + sh + g4.z;
            val.w = acc[i].w * s1 + sh + g4.w;
            val.x = (val.x > 0.f) ? val.x : 0.1f * val.x;
            val.y = (val.y > 0.f) ? val.y : 0.1f * val.y;
            val.z = (val.z > 0.f) ? val.z : 0.1f * val.z;
            val.w = (val.w > 0.f) ? val.w : 0.1f * val.w;
            *(float4*)(zp + (size_t)q * V_) = val;
        }
    }
}

// ---------------------------------------------------------------------------
// K5: out = leaky(bn(ff_w @ y3 + ff_b) + g), in-place on d_out
//     v2: ff_w staged in LDS (16 KB), unroll-2 o-loop
// ---------------------------------------------------------------------------
__global__ __launch_bounds__(256) void k5_ff(
    const float* __restrict__ g_ws, const float* __restrict__ fw, const float* __restrict__ fb,
    const float* __restrict__ bng, const float* __restrict__ bnb,
    const float* __restrict__ bnm, const float* __restrict__ bnv,
    float* __restrict__ io)
{
    __shared__ float ws[C_ * C_];            // 16 KB
    const int t = blockIdx.x, n = blockIdx.y;
    const int tid = threadIdx.x;
    {
        const float4* src = (const float4*)fw;
        float4* dst = (float4*)ws;
#pragma unroll
        for (int i = 0; i < 4; ++i) dst[tid + i * 256] = src[tid + i * 256];
    }
    __syncthreads();

    const int v = tid;
    if (v >= V_) return;
    float yc[C_];
    float* bp = io + (size_t)n * CTV_ + (size_t)t * V_ + v;
#pragma unroll
    for (int a = 0; a < C_; ++a) yc[a] = bp[(size_t)a * TV_];
    const float* gp = g_ws + (size_t)n * CTV_ + (size_t)t * V_ + v;
#pragma unroll 2
    for (int o = 0; o < C_; ++o) {
        float acc = fb[o];
        const float* wr = ws + o * C_;
#pragma unroll
        for (int a = 0; a < C_; ++a) acc = fmaf(wr[a], yc[a], acc);
        const float s1 = bng[o] * rsqrtf(bnv[o] + EPS_);
        float val = acc * s1 + (bnb[o] - bnm[o] * s1) + gp[(size_t)o * TV_];
        bp[(size_t)o * TV_] = (val > 0.f) ? val : 0.1f * val;
    }
}

// ---------------------------------------------------------------------------
extern "C" void kernel_launch(void* const* d_in, const int* in_sizes, int n_in,
                              void* d_out, int out_size, void* d_ws, size_t ws_size,
                              hipStream_t stream)
{
    (void)in_sizes; (void)n_in; (void)out_size; (void)ws_size;
    const float* x      = (const float*)d_in[0];
    const float* A      = (const float*)d_in[1];
    const float* gcn_w  = (const float*)d_in[2];
    const float* gcn_b  = (const float*)d_in[3];
    const float* gcn_g  = (const float*)d_in[4];
    const float* gcn_bb = (const float*)d_in[5];
    const float* gcn_m  = (const float*)d_in[6];
    const float* gcn_v  = (const float*)d_in[7];
    const float* pe     = (const float*)d_in[8];
    const float* qkv_w  = (const float*)d_in[9];
    const float* qkv_b  = (const float*)d_in[10];
    const float* alphas = (const float*)d_in[11];
    const float* att1s  = (const float*)d_in[12];
    const float* on_w   = (const float*)d_in[13];
    const float* on_b   = (const float*)d_in[14];
    const float* on_g   = (const float*)d_in[15];
    const float* on_bb  = (const float*)d_in[16];
    const float* on_m   = (const float*)d_in[17];
    const float* on_v   = (const float*)d_in[18];
    const float* ff_w   = (const float*)d_in[19];
    const float* ff_b   = (const float*)d_in[20];
    const float* ff_g   = (const float*)d_in[21];
    const float* ff_bb  = (const float*)d_in[22];
    const float* ff_m   = (const float*)d_in[23];
    const float* ff_v   = (const float*)d_in[24];
    float* out = (float*)d_out;

    float* g_ws    = (float*)d_ws;                         // 26,738,688 f
    float* qk_ws   = g_ws   + (size_t)N_ * CTV_;           // 40,108,032 f
    float* part_ws = qk_ws  + (size_t)N_ * 96 * TV_;       //  3,145,728 f
    float* att_ws  = part_ws + (size_t)8 * NH_ * 4096;     //    393,216 f
    float* P_ws    = qk_ws;                                // alias (qk dead after k3)
    __bf16* h_ws   = (__bf16*)qk_ws;                       // alias (dead before k2 writes)
    __bf16* Apad   = (__bf16*)part_ws;                     // alias (dead before k3a writes)

    k0_cvtA<<<dim3(UP_), 224, 0, stream>>>(A, Apad);
    k1a_h  <<<dim3(T_, N_), 256, 0, stream>>>(x, gcn_w, gcn_b, h_ws);
    k1b_mfma<<<dim3(2048), 256, 0, stream>>>(h_ws, Apad, x,
                                             gcn_g, gcn_bb, gcn_m, gcn_v, g_ws);
    k2_qkv<<<dim3(T_, N_, 4), 256, 0, stream>>>(g_ws, pe, qkv_w, qkv_b, qk_ws);
    k3_att_part<<<dim3(8, N_, 12), 64, 0, stream>>>(qk_ws, part_ws);
    k3_att_fin<<<dim3((NH_ * 4096) / 256), 256, 0, stream>>>(part_ws, alphas, att1s, att_ws);

    for (int chunk = 0; chunk < 2; ++chunk) {
        const int nb = chunk * 16;
        k4a_pw<<<dim3(T_, 16, 4), 256, 0, stream>>>(g_ws + (size_t)nb * CTV_, on_w, P_ws);
        k4b_apply<<<dim3(64, 16), 256, 0, stream>>>(
            P_ws, att_ws + (size_t)nb * H_ * 4096, g_ws + (size_t)nb * CTV_,
            on_b, on_g, on_bb, on_m, on_v, out + (size_t)nb * CTV_);
    }
    k5_ff<<<dim3(T_, N_), 256, 0, stream>>>(g_ws, ff_w, ff_b, ff_g, ff_bb, ff_m, ff_v, out);
}

// Round 5
// 1415.956 us; speedup vs baseline: 1.5052x; 1.0767x over previous
//
#include <hip/hip_runtime.h>

#define N_ 32
#define C_ 64
#define T_ 64
#define V_ 204
#define H_ 3
#define TV_ (T_ * V_)          // 13056
#define CTV_ (C_ * TV_)        // 835584
#define VG_ (V_ / 4)           // 51
#define NH_ (N_ * H_)          // 96
#define EPS_ 1e-5f
#define ATT_SC_ (1.0f / 3264.0f)
#define STV_ (H_ * TV_)        // 39168
#define KP_ 224                // padded K (v) for MFMA
#define UP_ 208                // padded u rows of A

typedef __bf16 bf16x8 __attribute__((ext_vector_type(8)));
typedef float  f32x4  __attribute__((ext_vector_type(4)));

// ---------------------------------------------------------------------------
// K0: Apad[u][v] = bf16(A[u][v]) zero-padded to 208x224
// ---------------------------------------------------------------------------
__global__ __launch_bounds__(224) void k0_cvtA(
    const float* __restrict__ A, __bf16* __restrict__ Apad)
{
    const int u = blockIdx.x;       // 0..207
    const int v = threadIdx.x;      // 0..223
    float val = (u < V_ && v < V_) ? A[u * V_ + v] : 0.f;
    Apad[u * KP_ + v] = (__bf16)val;
}

// ---------------------------------------------------------------------------
// K0b: Wbf = bf16(qkv_w), 96x64
// ---------------------------------------------------------------------------
__global__ __launch_bounds__(256) void k0b_cvtW(
    const float* __restrict__ qw, __bf16* __restrict__ Wbf)
{
    const int i = blockIdx.x * 256 + threadIdx.x;
    if (i < 96 * C_) Wbf[i] = (__bf16)qw[i];
}

// ---------------------------------------------------------------------------
// K1a: h[r][v] = bf16(bias[c] + sum_a W[c,a] x[n,a,t,v]), r=(n,c,t), row KP_
//      v2: W staged in LDS (16 KB), unroll-2 c-loop
// ---------------------------------------------------------------------------
__global__ __launch_bounds__(256) void k1a_h(
    const float* __restrict__ x, const float* __restrict__ W,
    const float* __restrict__ bias, __bf16* __restrict__ h)
{
    __shared__ float ws[C_ * C_];            // 16 KB
    const int t = blockIdx.x, n = blockIdx.y;
    const int tid = threadIdx.x;
    {
        const float4* src = (const float4*)W;
        float4* dst = (float4*)ws;
#pragma unroll
        for (int i = 0; i < 4; ++i) dst[tid + i * 256] = src[tid + i * 256];
    }
    __syncthreads();

    const int v = tid;
    if (v >= KP_) return;
    __bf16* hp = h + ((size_t)n * 4096 + t) * KP_ + v;   // + c*64*KP_ per row
    if (v >= V_) {
#pragma unroll 1
        for (int c = 0; c < C_; ++c) hp[(size_t)c * 64 * KP_] = (__bf16)0.f;
        return;
    }
    float xc[C_];
    const float* xp = x + (size_t)n * CTV_ + (size_t)t * V_ + v;
#pragma unroll
    for (int a = 0; a < C_; ++a) xc[a] = xp[(size_t)a * TV_];
#pragma unroll 2
    for (int c = 0; c < C_; ++c) {
        float acc = bias[c];
        const float* wr = ws + c * C_;
#pragma unroll
        for (int a = 0; a < C_; ++a) acc = fmaf(wr[a], xc[a], acc);
        hp[(size_t)c * 64 * KP_] = (__bf16)acc;
    }
}

// ---------------------------------------------------------------------------
// K1b: G[r,u] = sum_v h[r,v] * Apad[u,v]  (MFMA 16x16x32 bf16)
//      g = relu(s*G + sh + x) fused epilogue. 2048 blocks x 256 thr, no LDS.
// ---------------------------------------------------------------------------
__global__ __launch_bounds__(256) void k1b_mfma(
    const __bf16* __restrict__ h, const __bf16* __restrict__ Apad,
    const float* __restrict__ x,
    const float* __restrict__ bng, const float* __restrict__ bnb,
    const float* __restrict__ bnm, const float* __restrict__ bnv,
    float* __restrict__ g_out)
{
    const int wave = threadIdx.x >> 6;
    const int lane = threadIdx.x & 63;
    const int l16  = lane & 15;
    const int quad = lane >> 4;

    const __bf16* hA = h + (size_t)(blockIdx.x * 64 + wave * 16 + l16) * KP_ + quad * 8;
    const __bf16* Bp = Apad + (size_t)l16 * KP_ + quad * 8;

    f32x4 acc[13];
#pragma unroll
    for (int j = 0; j < 13; ++j) acc[j] = (f32x4){0.f, 0.f, 0.f, 0.f};

#pragma unroll 1
    for (int kc = 0; kc < 7; ++kc) {
        const bf16x8 af = *(const bf16x8*)(hA + kc * 32);
        bf16x8 bf[13];
#pragma unroll
        for (int j = 0; j < 13; ++j)
            bf[j] = *(const bf16x8*)(Bp + (size_t)j * 16 * KP_ + kc * 32);
#pragma unroll
        for (int j = 0; j < 13; ++j)
            acc[j] = __builtin_amdgcn_mfma_f32_16x16x32_bf16(af, bf[j], acc[j], 0, 0, 0);
    }

    // epilogue: block covers exactly one (n,c), t = 0..63
    const int c = blockIdx.x & 63;
    const float s1 = bng[c] * rsqrtf(bnv[c] + EPS_);
    const float sh = bnb[c] - bnm[c] * s1;
    const int rbase = blockIdx.x * 64 + wave * 16 + quad * 4;

#pragma unroll 1
    for (int j = 0; j < 13; ++j) {
        const int u = j * 16 + l16;
        if (u < V_) {
#pragma unroll
            for (int i = 0; i < 4; ++i) {
                const size_t r = (size_t)(rbase + i);
                const float val = acc[j][i] * s1 + sh + x[r * V_ + u];
                g_out[r * V_ + u] = fmaxf(val, 0.f);
            }
        }
    }
}

// ---------------------------------------------------------------------------
// K2 (v3, MFMA): qk[(n,tv), j] = sum_c bf16(g+pe)[tv,c] * Wbf[j,c] + qb[j]
//   M = N*TV rows (64/block, 16/wave), N = 96 (6 j-tiles), K = 64 (2 chunks).
//   A-frags gathered directly from global (no LDS, g read exactly once).
//   Output layout [n, j, t, v] fp32 — unchanged for k3.
// ---------------------------------------------------------------------------
__global__ __launch_bounds__(256) void k2_mfma(
    const float* __restrict__ g_ws, const float* __restrict__ pe,
    const __bf16* __restrict__ Wbf, const float* __restrict__ qb,
    float* __restrict__ qk_ws)
{
    const int bx  = blockIdx.x;            // 0..6527
    const int n   = bx / 204;
    const int tvb = (bx % 204) * 64;
    const int wave = threadIdx.x >> 6;
    const int lane = threadIdx.x & 63;
    const int l16  = lane & 15;
    const int quad = lane >> 4;

    // A fragments: row tv = tvb + wave*16 + l16, k = kc*32 + quad*8 + e
    const int tv = tvb + wave * 16 + l16;
    const float* gp = g_ws + (size_t)n * CTV_ + tv;
    const float* pp = pe + tv;
    bf16x8 a[2];
#pragma unroll
    for (int kc = 0; kc < 2; ++kc) {
#pragma unroll
        for (int e = 0; e < 8; ++e) {
            const int c = kc * 32 + quad * 8 + e;
            a[kc][e] = (__bf16)(gp[(size_t)c * TV_] + pp[(size_t)c * TV_]);
        }
    }

    f32x4 acc[6];
#pragma unroll
    for (int jt = 0; jt < 6; ++jt) acc[jt] = (f32x4){0.f, 0.f, 0.f, 0.f};

#pragma unroll
    for (int kc = 0; kc < 2; ++kc) {
#pragma unroll
        for (int jt = 0; jt < 6; ++jt) {
            const bf16x8 b = *(const bf16x8*)(Wbf + (size_t)(jt * 16 + l16) * C_ + kc * 32 + quad * 8);
            acc[jt] = __builtin_amdgcn_mfma_f32_16x16x32_bf16(a[kc], b, acc[jt], 0, 0, 0);
        }
    }

    // store: row tv = tvb + wave*16 + quad*4 + i, col j = jt*16 + l16
    const int rrow = tvb + wave * 16 + quad * 4;
#pragma unroll
    for (int jt = 0; jt < 6; ++jt) {
        const int j = jt * 16 + l16;
        const float bias = qb[j];
        float* op = qk_ws + (size_t)(n * 96 + j) * TV_ + rrow;
        float4 o;
        o.x = acc[jt][0] + bias;
        o.y = acc[jt][1] + bias;
        o.z = acc[jt][2] + bias;
        o.w = acc[jt][3] + bias;
        *(float4*)op = o;
    }
}

// ---------------------------------------------------------------------------
// K3a: att partials; K3b: finalize
// ---------------------------------------------------------------------------
__global__ __launch_bounds__(64) void k3_att_part(
    const float* __restrict__ qk_ws, float* __restrict__ part)
{
    const int qcg = blockIdx.x;
    const int n = blockIdx.y;
    const int h  = blockIdx.z >> 2;
    const int wv = blockIdx.z & 3;
    const int q = threadIdx.x;
    float acc[16];
#pragma unroll
    for (int i = 0; i < 16; ++i) acc[i] = 0.f;

#pragma unroll 1
    for (int qc2 = 0; qc2 < 2; ++qc2) {
        const int qc = qcg * 2 + qc2;
        const float* Qp = qk_ws + (size_t)(n * 96 + h * 16 + qc) * TV_;
        const float* Kp = qk_ws + (size_t)(n * 96 + 48 + h * 16 + qc) * TV_;
#pragma unroll 1
        for (int vc = 0; vc < 3; ++vc) {
            const int v0 = vc * 68;
            float kr[68];
            const float* kp = Kp + (size_t)q * V_ + v0;
#pragma unroll
            for (int m = 0; m < 17; ++m) {
                float4 f = *(const float4*)(kp + m * 4);
                kr[m * 4 + 0] = f.x; kr[m * 4 + 1] = f.y;
                kr[m * 4 + 2] = f.z; kr[m * 4 + 3] = f.w;
            }
#pragma unroll 1
            for (int ti = 0; ti < 16; ++ti) {
                const int tt = wv * 16 + ti;
                const float* qp = Qp + (size_t)tt * V_ + v0;
                float a = acc[ti];
#pragma unroll
                for (int vv = 0; vv < 68; ++vv) a = fmaf(qp[vv], kr[vv], a);
                acc[ti] = a;
            }
        }
    }
    float* pp = part + ((size_t)qcg * NH_ + (size_t)(n * H_ + h)) * 4096;
#pragma unroll
    for (int ti = 0; ti < 16; ++ti) pp[(wv * 16 + ti) * 64 + q] = acc[ti];
}

__global__ __launch_bounds__(256) void k3_att_fin(
    const float* __restrict__ part, const float* __restrict__ alphas,
    const float* __restrict__ att1s, float* __restrict__ att_ws)
{
    const int i = blockIdx.x * 256 + threadIdx.x;
    float s = 0.f;
#pragma unroll
    for (int p = 0; p < 8; ++p) s += part[(size_t)p * NH_ * 4096 + i];
    const int nh = i >> 12;
    const int h  = nh % H_;
    const int tq = i & 4095;
    att_ws[i] = tanhf(s * ATT_SC_) * alphas[h] + att1s[h * 4096 + tq];
}

// ---------------------------------------------------------------------------
// K4a: P[n',o,s,t,v] = sum_c on_w[o, s*64+c] * g[n,c,t,v]
//      v2: 4-way o-split (gridDim.z), on_w slice staged in LDS (float4),
//      unroll-2 o-loop
// ---------------------------------------------------------------------------
__global__ __launch_bounds__(256) void k4a_pw(
    const float* __restrict__ g_chunk,
    const float* __restrict__ onw,
    float* __restrict__ P)
{
    __shared__ float ws[16 * 192];
    const int t = blockIdx.x, np = blockIdx.y, og = blockIdx.z;
    const int o0 = og * 16;
    const int tid = threadIdx.x;

    // stage on_w[o0 .. o0+16) rows (16 x 192 = 3072 floats = 768 float4)
    {
        const float4* src = (const float4*)(onw + (size_t)o0 * 192);
        float4* dst = (float4*)ws;
#pragma unroll
        for (int i = 0; i < 3; ++i)
            dst[tid + i * 256] = src[tid + i * 256];
    }
    __syncthreads();

    const int v = tid;
    if (v >= V_) return;

    float gc[C_];
    const float* gp = g_chunk + (size_t)np * CTV_ + (size_t)t * V_ + v;
#pragma unroll
    for (int c = 0; c < C_; ++c) gc[c] = gp[(size_t)c * TV_];

    float* Pp = P + (size_t)np * 64 * STV_ + (size_t)t * V_ + v;
#pragma unroll 2
    for (int oo = 0; oo < 16; ++oo) {
        const int o = o0 + oo;
        float acc0 = 0.f, acc1 = 0.f, acc2 = 0.f;
        const float* wr = ws + oo * 192;
#pragma unroll
        for (int c = 0; c < C_; ++c) {
            acc0 = fmaf(wr[c],       gc[c], acc0);
            acc1 = fmaf(wr[64 + c],  gc[c], acc1);
            acc2 = fmaf(wr[128 + c], gc[c], acc2);
        }
        float* po = Pp + (size_t)o * STV_;
        po[0]               = acc0;
        po[(size_t)TV_]     = acc1;
        po[(size_t)2 * TV_] = acc2;
    }
}

// ---------------------------------------------------------------------------
// K4b: z[n,o,q,v] = sum_st att[n,s,t,q] * P[n',o,st,v]; fused epilogue
// ---------------------------------------------------------------------------
__global__ __launch_bounds__(256) void k4b_apply(
    const float* __restrict__ P,
    const float* __restrict__ att_chunk,
    const float* __restrict__ g_chunk,
    const float* __restrict__ onb,
    const float* __restrict__ bng, const float* __restrict__ bnb,
    const float* __restrict__ bnm, const float* __restrict__ bnv,
    float* __restrict__ out_chunk)
{
    __shared__ float att_s[192 * 64];
    const int o = blockIdx.x, np = blockIdx.y;
    const int tid = threadIdx.x;

    {
        const float4* src = (const float4*)(att_chunk + (size_t)np * (H_ * 4096));
        float4* dst = (float4*)att_s;
#pragma unroll
        for (int i = 0; i < 12; ++i) dst[tid + i * 256] = src[tid + i * 256];
    }
    __syncthreads();

    if (tid < 204) {
        const int vg = tid % 51, qg = tid / 51;
        const int v0 = vg * 4, q0 = qg * 16;

        float4 acc[16];
#pragma unroll
        for (int i = 0; i < 16; ++i) acc[i] = make_float4(0.f, 0.f, 0.f, 0.f);

        const float* Pp = P + (size_t)(np * 64 + o) * STV_ + v0;
#pragma unroll 2
        for (int st = 0; st < 192; ++st) {
            const float4 p = *(const float4*)(Pp + (size_t)st * V_);
            const float* ar = att_s + st * 64 + q0;
#pragma unroll
            for (int j = 0; j < 4; ++j) {
                const float4 a4 = *(const float4*)(ar + j * 4);
                acc[j * 4 + 0].x = fmaf(a4.x, p.x, acc[j * 4 + 0].x);
                acc[j * 4 + 0].y = fmaf(a4.x, p.y, acc[j * 4 + 0].y);
                acc[j * 4 + 0].z = fmaf(a4.x, p.z, acc[j * 4 + 0].z);
                acc[j * 4 + 0].w = fmaf(a4.x, p.w, acc[j * 4 + 0].w);
                acc[j * 4 + 1].x = fmaf(a4.y, p.x, acc[j * 4 + 1].x);
                acc[j * 4 + 1].y = fmaf(a4.y, p.y, acc[j * 4 + 1].y);
                acc[j * 4 + 1].z = fmaf(a4.y, p.z, acc[j * 4 + 1].z);
                acc[j * 4 + 1].w = fmaf(a4.y, p.w, acc[j * 4 + 1].w);
                acc[j * 4 + 2].x = fmaf(a4.z, p.x, acc[j * 4 + 2].x);
                acc[j * 4 + 2].y = fmaf(a4.z, p.y, acc[j * 4 + 2].y);
                acc[j * 4 + 2].z = fmaf(a4.z, p.z, acc[j * 4 + 2].z);
                acc[j * 4 + 2].w = fmaf(a4.z, p.w, acc[j * 4 + 2].w);
                acc[j * 4 + 3].x = fmaf(a4.w, p.x, acc[j * 4 + 3].x);
                acc[j * 4 + 3].y = fmaf(a4.w, p.y, acc[j * 4 + 3].y);
                acc[j * 4 + 3].z = fmaf(a4.w, p.z, acc[j * 4 + 3].z);
                acc[j * 4 + 3].w = fmaf(a4.w, p.w, acc[j * 4 + 3].w);
            }
        }

        const float s1 = bng[o] * rsqrtf(bnv[o] + EPS_);
        const float sh = onb[o] * s1 + bnb[o] - bnm[o] * s1;
        const float* gp = g_chunk + (size_t)np * CTV_ + (size_t)o * TV_ + v0;
        float* zp = out_chunk + (size_t)np * CTV_ + (size_t)o * TV_ + v0;
#pragma unroll 1
        for (int i = 0; i < 16; ++i) {
            const int q = q0 + i;
            const float4 g4 = *(const float4*)(gp + (size_t)q * V_);
            float4 val;
            val.x = acc[i].x * s1 + sh + g4.x;
            val.y = acc[i].y * s1 + sh + g4.y;
            val.z = acc[i].z * s1 + sh + g4.z;
            val.w = acc[i].w * s1 + sh + g4.w;
            val.x = (val.x > 0.f) ? val.x : 0.1f * val.x;
            val.y = (val.y > 0.f) ? val.y : 0.1f * val.y;
            val.z = (val.z > 0.f) ? val.z : 0.1f * val.z;
            val.w = (val.w > 0.f) ? val.w : 0.1f * val.w;
            *(float4*)(zp + (size_t)q * V_) = val;
        }
    }
}

// ---------------------------------------------------------------------------
// K5: out = leaky(bn(ff_w @ y3 + ff_b) + g), in-place on d_out
//     v2: ff_w staged in LDS (16 KB), unroll-2 o-loop
// ---------------------------------------------------------------------------
__global__ __launch_bounds__(256) void k5_ff(
    const float* __restrict__ g_ws, const float* __restrict__ fw, const float* __restrict__ fb,
    const float* __restrict__ bng, const float* __restrict__ bnb,
    const float* __restrict__ bnm, const float* __restrict__ bnv,
    float* __restrict__ io)
{
    __shared__ float ws[C_ * C_];            // 16 KB
    const int t = blockIdx.x, n = blockIdx.y;
    const int tid = threadIdx.x;
    {
        const float4* src = (const float4*)fw;
        float4* dst = (float4*)ws;
#pragma unroll
        for (int i = 0; i < 4; ++i) dst[tid + i * 256] = src[tid + i * 256];
    }
    __syncthreads();

    const int v = tid;
    if (v >= V_) return;
    float yc[C_];
    float* bp = io + (size_t)n * CTV_ + (size_t)t * V_ + v;
#pragma unroll
    for (int a = 0; a < C_; ++a) yc[a] = bp[(size_t)a * TV_];
    const float* gp = g_ws + (size_t)n * CTV_ + (size_t)t * V_ + v;
#pragma unroll 2
    for (int o = 0; o < C_; ++o) {
        float acc = fb[o];
        const float* wr = ws + o * C_;
#pragma unroll
        for (int a = 0; a < C_; ++a) acc = fmaf(wr[a], yc[a], acc);
        const float s1 = bng[o] * rsqrtf(bnv[o] + EPS_);
        float val = acc * s1 + (bnb[o] - bnm[o] * s1) + gp[(size_t)o * TV_];
        bp[(size_t)o * TV_] = (val > 0.f) ? val : 0.1f * val;
    }
}

// ---------------------------------------------------------------------------
extern "C" void kernel_launch(void* const* d_in, const int* in_sizes, int n_in,
                              void* d_out, int out_size, void* d_ws, size_t ws_size,
                              hipStream_t stream)
{
    (void)in_sizes; (void)n_in; (void)out_size; (void)ws_size;
    const float* x      = (const float*)d_in[0];
    const float* A      = (const float*)d_in[1];
    const float* gcn_w  = (const float*)d_in[2];
    const float* gcn_b  = (const float*)d_in[3];
    const float* gcn_g  = (const float*)d_in[4];
    const float* gcn_bb = (const float*)d_in[5];
    const float* gcn_m  = (const float*)d_in[6];
    const float* gcn_v  = (const float*)d_in[7];
    const float* pe     = (const float*)d_in[8];
    const float* qkv_w  = (const float*)d_in[9];
    const float* qkv_b  = (const float*)d_in[10];
    const float* alphas = (const float*)d_in[11];
    const float* att1s  = (const float*)d_in[12];
    const float* on_w   = (const float*)d_in[13];
    const float* on_b   = (const float*)d_in[14];
    const float* on_g   = (const float*)d_in[15];
    const float* on_bb  = (const float*)d_in[16];
    const float* on_m   = (const float*)d_in[17];
    const float* on_v   = (const float*)d_in[18];
    const float* ff_w   = (const float*)d_in[19];
    const float* ff_b   = (const float*)d_in[20];
    const float* ff_g   = (const float*)d_in[21];
    const float* ff_bb  = (const float*)d_in[22];
    const float* ff_m   = (const float*)d_in[23];
    const float* ff_v   = (const float*)d_in[24];
    float* out = (float*)d_out;

    float* g_ws    = (float*)d_ws;                         // 26,738,688 f
    float* qk_ws   = g_ws   + (size_t)N_ * CTV_;           // 40,108,032 f
    float* part_ws = qk_ws  + (size_t)N_ * 96 * TV_;       //  3,145,728 f
    float* att_ws  = part_ws + (size_t)8 * NH_ * 4096;     //    393,216 f
    float* P_ws    = qk_ws;                                // alias (qk dead after k3)
    __bf16* h_ws   = (__bf16*)qk_ws;                       // alias (dead before k2 writes)
    __bf16* Apad   = (__bf16*)part_ws;                     // alias (dead before k3a writes)
    __bf16* Wbf    = Apad + (size_t)UP_ * KP_;             // alias (dead before k3a writes)

    k0_cvtA<<<dim3(UP_), 224, 0, stream>>>(A, Apad);
    k0b_cvtW<<<dim3(24), 256, 0, stream>>>(qkv_w, Wbf);
    k1a_h  <<<dim3(T_, N_), 256, 0, stream>>>(x, gcn_w, gcn_b, h_ws);
    k1b_mfma<<<dim3(2048), 256, 0, stream>>>(h_ws, Apad, x,
                                             gcn_g, gcn_bb, gcn_m, gcn_v, g_ws);
    k2_mfma<<<dim3(6528), 256, 0, stream>>>(g_ws, pe, Wbf, qkv_b, qk_ws);
    k3_att_part<<<dim3(8, N_, 12), 64, 0, stream>>>(qk_ws, part_ws);
    k3_att_fin<<<dim3((NH_ * 4096) / 256), 256, 0, stream>>>(part_ws, alphas, att1s, att_ws);

    for (int chunk = 0; chunk < 2; ++chunk) {
        const int nb = chunk * 16;
        k4a_pw<<<dim3(T_, 16, 4), 256, 0, stream>>>(g_ws + (size_t)nb * CTV_, on_w, P_ws);
        k4b_apply<<<dim3(64, 16), 256, 0, stream>>>(
            P_ws, att_ws + (size_t)nb * H_ * 4096, g_ws + (size_t)nb * CTV_,
            on_b, on_g, on_bb, on_m, on_v, out + (size_t)nb * CTV_);
    }
    k5_ff<<<dim3(T_, N_), 256, 0, stream>>>(g_ws, ff_w, ff_b, ff_g, ff_bb, ff_m, ff_v, out);
}

// Round 7
// 1059.267 us; speedup vs baseline: 2.0121x; 1.3367x over previous
//
#include <hip/hip_runtime.h>

#define N_ 32
#define C_ 64
#define T_ 64
#define V_ 204
#define H_ 3
#define TV_ (T_ * V_)          // 13056
#define CTV_ (C_ * TV_)        // 835584
#define VG_ (V_ / 4)           // 51
#define NH_ (N_ * H_)          // 96
#define EPS_ 1e-5f
#define ATT_SC_ (1.0f / 3264.0f)
#define STV_ (H_ * TV_)        // 39168
#define KP_ 224                // padded K (v) for MFMA
#define UP_ 208                // padded u rows of A

typedef __bf16 bf16x8 __attribute__((ext_vector_type(8)));
typedef float  f32x4  __attribute__((ext_vector_type(4)));

// ---------------------------------------------------------------------------
// K0: Apad[u][v] = bf16(A[u][v]) zero-padded to 208x224
// ---------------------------------------------------------------------------
__global__ __launch_bounds__(224) void k0_cvtA(
    const float* __restrict__ A, __bf16* __restrict__ Apad)
{
    const int u = blockIdx.x;       // 0..207
    const int v = threadIdx.x;      // 0..223
    float val = (u < V_ && v < V_) ? A[u * V_ + v] : 0.f;
    Apad[u * KP_ + v] = (__bf16)val;
}

// ---------------------------------------------------------------------------
// K0w: fused weight conversions.
//   i < 6144:        Wbf[i]    = bf16(qkv_w[i])           (96x64)
//   6144 <= i:       onw_bf[j] = bf16(on_w[o][s*64+c]),   j = i-6144 (192x64)
// ---------------------------------------------------------------------------
__global__ __launch_bounds__(256) void k0w_cvt(
    const float* __restrict__ qw, const float* __restrict__ onw,
    __bf16* __restrict__ Wbf, __bf16* __restrict__ onw_bf)
{
    const int i = blockIdx.x * 256 + threadIdx.x;   // 0..18431
    if (i < 96 * C_) {
        Wbf[i] = (__bf16)qw[i];
    } else {
        const int j = i - 96 * C_;                  // 0..12287
        const int c = j & 63, r = j >> 6, o = r & 63, s = r >> 6;
        onw_bf[j] = (__bf16)onw[o * 192 + s * 64 + c];
    }
}

// ---------------------------------------------------------------------------
// K1a: h[r][v] = bf16(bias[c] + sum_a W[c,a] x[n,a,t,v]), r=(n,c,t), row KP_
//      v2: W staged in LDS (16 KB), unroll-2 c-loop
// ---------------------------------------------------------------------------
__global__ __launch_bounds__(256) void k1a_h(
    const float* __restrict__ x, const float* __restrict__ W,
    const float* __restrict__ bias, __bf16* __restrict__ h)
{
    __shared__ float ws[C_ * C_];            // 16 KB
    const int t = blockIdx.x, n = blockIdx.y;
    const int tid = threadIdx.x;
    {
        const float4* src = (const float4*)W;
        float4* dst = (float4*)ws;
#pragma unroll
        for (int i = 0; i < 4; ++i) dst[tid + i * 256] = src[tid + i * 256];
    }
    __syncthreads();

    const int v = tid;
    if (v >= KP_) return;
    __bf16* hp = h + ((size_t)n * 4096 + t) * KP_ + v;   // + c*64*KP_ per row
    if (v >= V_) {
#pragma unroll 1
        for (int c = 0; c < C_; ++c) hp[(size_t)c * 64 * KP_] = (__bf16)0.f;
        return;
    }
    float xc[C_];
    const float* xp = x + (size_t)n * CTV_ + (size_t)t * V_ + v;
#pragma unroll
    for (int a = 0; a < C_; ++a) xc[a] = xp[(size_t)a * TV_];
#pragma unroll 2
    for (int c = 0; c < C_; ++c) {
        float acc = bias[c];
        const float* wr = ws + c * C_;
#pragma unroll
        for (int a = 0; a < C_; ++a) acc = fmaf(wr[a], xc[a], acc);
        hp[(size_t)c * 64 * KP_] = (__bf16)acc;
    }
}

// ---------------------------------------------------------------------------
// K1b: G[r,u] = sum_v h[r,v] * Apad[u,v]  (MFMA 16x16x32 bf16)
//      g = relu(s*G + sh + x) fused epilogue. 2048 blocks x 256 thr, no LDS.
// ---------------------------------------------------------------------------
__global__ __launch_bounds__(256) void k1b_mfma(
    const __bf16* __restrict__ h, const __bf16* __restrict__ Apad,
    const float* __restrict__ x,
    const float* __restrict__ bng, const float* __restrict__ bnb,
    const float* __restrict__ bnm, const float* __restrict__ bnv,
    float* __restrict__ g_out)
{
    const int wave = threadIdx.x >> 6;
    const int lane = threadIdx.x & 63;
    const int l16  = lane & 15;
    const int quad = lane >> 4;

    const __bf16* hA = h + (size_t)(blockIdx.x * 64 + wave * 16 + l16) * KP_ + quad * 8;
    const __bf16* Bp = Apad + (size_t)l16 * KP_ + quad * 8;

    f32x4 acc[13];
#pragma unroll
    for (int j = 0; j < 13; ++j) acc[j] = (f32x4){0.f, 0.f, 0.f, 0.f};

#pragma unroll 1
    for (int kc = 0; kc < 7; ++kc) {
        const bf16x8 af = *(const bf16x8*)(hA + kc * 32);
        bf16x8 bf[13];
#pragma unroll
        for (int j = 0; j < 13; ++j)
            bf[j] = *(const bf16x8*)(Bp + (size_t)j * 16 * KP_ + kc * 32);
#pragma unroll
        for (int j = 0; j < 13; ++j)
            acc[j] = __builtin_amdgcn_mfma_f32_16x16x32_bf16(af, bf[j], acc[j], 0, 0, 0);
    }

    // epilogue: block covers exactly one (n,c), t = 0..63
    const int c = blockIdx.x & 63;
    const float s1 = bng[c] * rsqrtf(bnv[c] + EPS_);
    const float sh = bnb[c] - bnm[c] * s1;
    const int rbase = blockIdx.x * 64 + wave * 16 + quad * 4;

#pragma unroll 1
    for (int j = 0; j < 13; ++j) {
        const int u = j * 16 + l16;
        if (u < V_) {
#pragma unroll
            for (int i = 0; i < 4; ++i) {
                const size_t r = (size_t)(rbase + i);
                const float val = acc[j][i] * s1 + sh + x[r * V_ + u];
                g_out[r * V_ + u] = fmaxf(val, 0.f);
            }
        }
    }
}

// ---------------------------------------------------------------------------
// K2 (MFMA): qk[(n,tv), j] = sum_c bf16(g+pe)[tv,c] * Wbf[j,c] + qb[j]
// ---------------------------------------------------------------------------
__global__ __launch_bounds__(256) void k2_mfma(
    const float* __restrict__ g_ws, const float* __restrict__ pe,
    const __bf16* __restrict__ Wbf, const float* __restrict__ qb,
    float* __restrict__ qk_ws)
{
    const int bx  = blockIdx.x;            // 0..6527
    const int n   = bx / 204;
    const int tvb = (bx % 204) * 64;
    const int wave = threadIdx.x >> 6;
    const int lane = threadIdx.x & 63;
    const int l16  = lane & 15;
    const int quad = lane >> 4;

    const int tv = tvb + wave * 16 + l16;
    const float* gp = g_ws + (size_t)n * CTV_ + tv;
    const float* pp = pe + tv;
    bf16x8 a[2];
#pragma unroll
    for (int kc = 0; kc < 2; ++kc) {
#pragma unroll
        for (int e = 0; e < 8; ++e) {
            const int c = kc * 32 + quad * 8 + e;
            a[kc][e] = (__bf16)(gp[(size_t)c * TV_] + pp[(size_t)c * TV_]);
        }
    }

    f32x4 acc[6];
#pragma unroll
    for (int jt = 0; jt < 6; ++jt) acc[jt] = (f32x4){0.f, 0.f, 0.f, 0.f};

#pragma unroll
    for (int kc = 0; kc < 2; ++kc) {
#pragma unroll
        for (int jt = 0; jt < 6; ++jt) {
            const bf16x8 b = *(const bf16x8*)(Wbf + (size_t)(jt * 16 + l16) * C_ + kc * 32 + quad * 8);
            acc[jt] = __builtin_amdgcn_mfma_f32_16x16x32_bf16(a[kc], b, acc[jt], 0, 0, 0);
        }
    }

    const int rrow = tvb + wave * 16 + quad * 4;
#pragma unroll
    for (int jt = 0; jt < 6; ++jt) {
        const int j = jt * 16 + l16;
        const float bias = qb[j];
        float* op = qk_ws + (size_t)(n * 96 + j) * TV_ + rrow;
        float4 o;
        o.x = acc[jt][0] + bias;
        o.y = acc[jt][1] + bias;
        o.z = acc[jt][2] + bias;
        o.w = acc[jt][3] + bias;
        *(float4*)op = o;
    }
}

// ---------------------------------------------------------------------------
// K3a: att partials; K3b: finalize + transpose to bf16 [n][q][s*64+t]
// ---------------------------------------------------------------------------
__global__ __launch_bounds__(64) void k3_att_part(
    const float* __restrict__ qk_ws, float* __restrict__ part)
{
    const int qcg = blockIdx.x;
    const int n = blockIdx.y;
    const int h  = blockIdx.z >> 2;
    const int wv = blockIdx.z & 3;
    const int q = threadIdx.x;
    float acc[16];
#pragma unroll
    for (int i = 0; i < 16; ++i) acc[i] = 0.f;

#pragma unroll 1
    for (int qc2 = 0; qc2 < 2; ++qc2) {
        const int qc = qcg * 2 + qc2;
        const float* Qp = qk_ws + (size_t)(n * 96 + h * 16 + qc) * TV_;
        const float* Kp = qk_ws + (size_t)(n * 96 + 48 + h * 16 + qc) * TV_;
#pragma unroll 1
        for (int vc = 0; vc < 3; ++vc) {
            const int v0 = vc * 68;
            float kr[68];
            const float* kp = Kp + (size_t)q * V_ + v0;
#pragma unroll
            for (int m = 0; m < 17; ++m) {
                float4 f = *(const float4*)(kp + m * 4);
                kr[m * 4 + 0] = f.x; kr[m * 4 + 1] = f.y;
                kr[m * 4 + 2] = f.z; kr[m * 4 + 3] = f.w;
            }
#pragma unroll 1
            for (int ti = 0; ti < 16; ++ti) {
                const int tt = wv * 16 + ti;
                const float* qp = Qp + (size_t)tt * V_ + v0;
                float a = acc[ti];
#pragma unroll
                for (int vv = 0; vv < 68; ++vv) a = fmaf(qp[vv], kr[vv], a);
                acc[ti] = a;
            }
        }
    }
    float* pp = part + ((size_t)qcg * NH_ + (size_t)(n * H_ + h)) * 4096;
#pragma unroll
    for (int ti = 0; ti < 16; ++ti) pp[(wv * 16 + ti) * 64 + q] = acc[ti];
}

__global__ __launch_bounds__(256) void k3_att_fin(
    const float* __restrict__ part, const float* __restrict__ alphas,
    const float* __restrict__ att1s, __bf16* __restrict__ att_bt)
{
    const int i = blockIdx.x * 256 + threadIdx.x;
    float s = 0.f;
#pragma unroll
    for (int p = 0; p < 8; ++p) s += part[(size_t)p * NH_ * 4096 + i];
    const int nh = i >> 12;
    const int h  = nh % H_;
    const int n  = nh / H_;
    const int tq = i & 4095;
    const int t  = tq >> 6;
    const int q  = tq & 63;
    const float val = tanhf(s * ATT_SC_) * alphas[h] + att1s[h * 4096 + tq];
    att_bt[((size_t)n * 64 + q) * 192 + h * 64 + t] = (__bf16)val;
}

// ---------------------------------------------------------------------------
// K4a (MFMA): P[np][(s*64+o)][tv] bf16 = sum_c onw_bf[(s,o)][c] * g[np][c][tv]
//   M=192 (12 m-tiles), cols 13056 (204 blocks x 64), K=64.
// ---------------------------------------------------------------------------
__global__ __launch_bounds__(256) void k4a_mfma(
    const float* __restrict__ g_chunk, const __bf16* __restrict__ onw_bf,
    __bf16* __restrict__ P)
{
    const int tvt = blockIdx.x;        // 0..203
    const int np  = blockIdx.y;        // 0..15
    const int wave = threadIdx.x >> 6;
    const int lane = threadIdx.x & 63;
    const int l16  = lane & 15;
    const int quad = lane >> 4;
    const int tv = tvt * 64 + wave * 16 + l16;

    // B-frags: g[c][tv], c = kc*32 + quad*8 + e (dword gathers, lane-coalesced)
    const float* gp = g_chunk + (size_t)np * CTV_ + tv;
    bf16x8 b[2];
#pragma unroll
    for (int kc = 0; kc < 2; ++kc) {
#pragma unroll
        for (int e = 0; e < 8; ++e)
            b[kc][e] = (__bf16)gp[(size_t)(kc * 32 + quad * 8 + e) * TV_];
    }

    __bf16* Pp = P + (size_t)np * 192 * TV_ + tv;
#pragma unroll
    for (int mt = 0; mt < 12; ++mt) {
        f32x4 acc = (f32x4){0.f, 0.f, 0.f, 0.f};
#pragma unroll
        for (int kc = 0; kc < 2; ++kc) {
            const bf16x8 a = *(const bf16x8*)(onw_bf + (mt * 16 + l16) * C_ + kc * 32 + quad * 8);
            acc = __builtin_amdgcn_mfma_f32_16x16x32_bf16(a, b[kc], acc, 0, 0, 0);
        }
#pragma unroll
        for (int i = 0; i < 4; ++i)
            Pp[(size_t)(mt * 16 + quad * 4 + i) * TV_] = (__bf16)acc[i];
    }
}

// ---------------------------------------------------------------------------
// K4b (MFMA): y[q,v] per (np,o) = sum_{k=0..191} att_bt[q][k] * P[(s,o)][t,v]
//   k = s*64+t; A = att_bt rows q (16B frags); B = P ushort gathers
//   (stride 408B, 32B-coalesced across lanes). Epilogue: bn+leaky+residual.
// ---------------------------------------------------------------------------
__global__ __launch_bounds__(256) void k4b_mfma(
    const __bf16* __restrict__ P,
    const __bf16* __restrict__ att_bt_chunk,   // [np][q][192]
    const float* __restrict__ g_chunk,
    const float* __restrict__ onb,
    const float* __restrict__ bng, const float* __restrict__ bnb,
    const float* __restrict__ bnm, const float* __restrict__ bnv,
    float* __restrict__ out_chunk)
{
    const int o  = blockIdx.x;   // 0..63
    const int np = blockIdx.y;   // 0..15
    const int wave = threadIdx.x >> 6;
    const int lane = threadIdx.x & 63;
    const int l16  = lane & 15;
    const int quad = lane >> 4;
    const int q0 = wave * 16;

    // A-frags: att_bt[q0+l16][kk*32 + quad*8 + e]
    const __bf16* ap = att_bt_chunk + ((size_t)np * 64 + q0 + l16) * 192 + quad * 8;
    bf16x8 a[6];
#pragma unroll
    for (int kk = 0; kk < 6; ++kk) a[kk] = *(const bf16x8*)(ap + kk * 32);

    // B base pointers per kk: row r = (kk>>1)*64 + o, t-base = (kk&1)*32 + quad*8
    const __bf16* bp[6];
#pragma unroll
    for (int kk = 0; kk < 6; ++kk)
        bp[kk] = P + ((size_t)np * 192 + (kk >> 1) * 64 + o) * TV_
                   + (size_t)((kk & 1) * 32 + quad * 8) * V_ + l16;

    f32x4 acc[13];
#pragma unroll
    for (int vt = 0; vt < 13; ++vt) acc[vt] = (f32x4){0.f, 0.f, 0.f, 0.f};

#pragma unroll
    for (int vt = 0; vt < 13; ++vt) {
#pragma unroll
        for (int kk = 0; kk < 6; ++kk) {
            bf16x8 b;
#pragma unroll
            for (int e = 0; e < 8; ++e) b[e] = bp[kk][e * V_ + vt * 16];
            acc[vt] = __builtin_amdgcn_mfma_f32_16x16x32_bf16(a[kk], b, acc[vt], 0, 0, 0);
        }
    }

    const float s1 = bng[o] * rsqrtf(bnv[o] + EPS_);
    const float sh = onb[o] * s1 + bnb[o] - bnm[o] * s1;
    const float* gp = g_chunk + (size_t)np * CTV_ + (size_t)o * TV_;
    float* zp = out_chunk + (size_t)np * CTV_ + (size_t)o * TV_;
    const int q = q0 + quad * 4;
#pragma unroll
    for (int vt = 0; vt < 13; ++vt) {
        const int v = vt * 16 + l16;
        if (v < V_) {
#pragma unroll
            for (int i = 0; i < 4; ++i) {
                float val = acc[vt][i] * s1 + sh + gp[(size_t)(q + i) * V_ + v];
                zp[(size_t)(q + i) * V_ + v] = (val > 0.f) ? val : 0.1f * val;
            }
        }
    }
}

// ---------------------------------------------------------------------------
// K5: out = leaky(bn(ff_w @ y3 + ff_b) + g), in-place on d_out
//     v2: ff_w staged in LDS (16 KB), unroll-2 o-loop
// ---------------------------------------------------------------------------
__global__ __launch_bounds__(256) void k5_ff(
    const float* __restrict__ g_ws, const float* __restrict__ fw, const float* __restrict__ fb,
    const float* __restrict__ bng, const float* __restrict__ bnb,
    const float* __restrict__ bnm, const float* __restrict__ bnv,
    float* __restrict__ io)
{
    __shared__ float ws[C_ * C_];            // 16 KB
    const int t = blockIdx.x, n = blockIdx.y;
    const int tid = threadIdx.x;
    {
        const float4* src = (const float4*)fw;
        float4* dst = (float4*)ws;
#pragma unroll
        for (int i = 0; i < 4; ++i) dst[tid + i * 256] = src[tid + i * 256];
    }
    __syncthreads();

    const int v = tid;
    if (v >= V_) return;
    float yc[C_];
    float* bp = io + (size_t)n * CTV_ + (size_t)t * V_ + v;
#pragma unroll
    for (int a = 0; a < C_; ++a) yc[a] = bp[(size_t)a * TV_];
    const float* gp = g_ws + (size_t)n * CTV_ + (size_t)t * V_ + v;
#pragma unroll 2
    for (int o = 0; o < C_; ++o) {
        float acc = fb[o];
        const float* wr = ws + o * C_;
#pragma unroll
        for (int a = 0; a < C_; ++a) acc = fmaf(wr[a], yc[a], acc);
        const float s1 = bng[o] * rsqrtf(bnv[o] + EPS_);
        float val = acc * s1 + (bnb[o] - bnm[o] * s1) + gp[(size_t)o * TV_];
        bp[(size_t)o * TV_] = (val > 0.f) ? val : 0.1f * val;
    }
}

// ---------------------------------------------------------------------------
extern "C" void kernel_launch(void* const* d_in, const int* in_sizes, int n_in,
                              void* d_out, int out_size, void* d_ws, size_t ws_size,
                              hipStream_t stream)
{
    (void)in_sizes; (void)n_in; (void)out_size; (void)ws_size;
    const float* x      = (const float*)d_in[0];
    const float* A      = (const float*)d_in[1];
    const float* gcn_w  = (const float*)d_in[2];
    const float* gcn_b  = (const float*)d_in[3];
    const float* gcn_g  = (const float*)d_in[4];
    const float* gcn_bb = (const float*)d_in[5];
    const float* gcn_m  = (const float*)d_in[6];
    const float* gcn_v  = (const float*)d_in[7];
    const float* pe     = (const float*)d_in[8];
    const float* qkv_w  = (const float*)d_in[9];
    const float* qkv_b  = (const float*)d_in[10];
    const float* alphas = (const float*)d_in[11];
    const float* att1s  = (const float*)d_in[12];
    const float* on_w   = (const float*)d_in[13];
    const float* on_b   = (const float*)d_in[14];
    const float* on_g   = (const float*)d_in[15];
    const float* on_bb  = (const float*)d_in[16];
    const float* on_m   = (const float*)d_in[17];
    const float* on_v   = (const float*)d_in[18];
    const float* ff_w   = (const float*)d_in[19];
    const float* ff_b   = (const float*)d_in[20];
    const float* ff_g   = (const float*)d_in[21];
    const float* ff_bb  = (const float*)d_in[22];
    const float* ff_m   = (const float*)d_in[23];
    const float* ff_v   = (const float*)d_in[24];
    float* out = (float*)d_out;

    float* g_ws    = (float*)d_ws;                         // 26,738,688 f
    float* qk_ws   = g_ws   + (size_t)N_ * CTV_;           // 40,108,032 f
    float* part_ws = qk_ws  + (size_t)N_ * 96 * TV_;       //  3,145,728 f
    float* att_ws  = part_ws + (size_t)8 * NH_ * 4096;     //    393,216 f
    __bf16* h_ws   = (__bf16*)qk_ws;                       // alias (dead before k2 writes)
    __bf16* P_bf   = (__bf16*)qk_ws;                       // alias (qk dead after k3a)
    __bf16* Apad   = (__bf16*)part_ws;                     // alias (dead before k3a writes)
    __bf16* Wbf    = Apad + (size_t)UP_ * KP_;             // alias (dead before k3a writes)
    __bf16* att_bt = (__bf16*)att_ws;                      // 786 KB (bf16 transposed att)
    __bf16* onw_bf = (__bf16*)att_ws + (size_t)NH_ * 4096; // +24 KB, survives k3

    k0_cvtA<<<dim3(UP_), 224, 0, stream>>>(A, Apad);
    k0w_cvt<<<dim3(72), 256, 0, stream>>>(qkv_w, on_w, Wbf, onw_bf);
    k1a_h  <<<dim3(T_, N_), 256, 0, stream>>>(x, gcn_w, gcn_b, h_ws);
    k1b_mfma<<<dim3(2048), 256, 0, stream>>>(h_ws, Apad, x,
                                             gcn_g, gcn_bb, gcn_m, gcn_v, g_ws);
    k2_mfma<<<dim3(6528), 256, 0, stream>>>(g_ws, pe, Wbf, qkv_b, qk_ws);
    k3_att_part<<<dim3(8, N_, 12), 64, 0, stream>>>(qk_ws, part_ws);
    k3_att_fin<<<dim3((NH_ * 4096) / 256), 256, 0, stream>>>(part_ws, alphas, att1s, att_bt);

    for (int chunk = 0; chunk < 2; ++chunk) {
        const int nb = chunk * 16;
        k4a_mfma<<<dim3(204, 16), 256, 0, stream>>>(
            g_ws + (size_t)nb * CTV_, onw_bf, P_bf);
        k4b_mfma<<<dim3(64, 16), 256, 0, stream>>>(
            P_bf, att_bt + (size_t)nb * 64 * 192, g_ws + (size_t)nb * CTV_,
            on_b, on_g, on_bb, on_m, on_v, out + (size_t)nb * CTV_);
    }
    k5_ff<<<dim3(T_, N_), 256, 0, stream>>>(g_ws, ff_w, ff_b, ff_g, ff_bb, ff_m, ff_v, out);
}

// Round 9
// 1004.224 us; speedup vs baseline: 2.1224x; 1.0548x over previous
//
#include <hip/hip_runtime.h>

#define N_ 32
#define C_ 64
#define T_ 64
#define V_ 204
#define H_ 3
#define TV_ (T_ * V_)          // 13056
#define CTV_ (C_ * TV_)        // 835584
#define NH_ (N_ * H_)          // 96
#define EPS_ 1e-5f
#define ATT_SC_ (1.0f / 3264.0f)
#define STV_ (H_ * TV_)        // 39168
#define KP_ 224                // padded K (v) for MFMA
#define UP_ 208                // padded u rows of A

typedef __bf16 bf16x8 __attribute__((ext_vector_type(8)));
typedef __bf16 bf16x4 __attribute__((ext_vector_type(4)));
typedef float  f32x4  __attribute__((ext_vector_type(4)));

// ---------------------------------------------------------------------------
// K0_all: fused conversions (270 blocks x 256 = 69120 threads)
//   i < 46592:  Apad[u*224+v] = bf16(A[u][v]) zero-padded (208x224)
//   next 6144:  Wbf = bf16(qkv_w)                          (96x64)
//   next 12288: onw_bf[(s*64+o)][c] = bf16(on_w[o][s*64+c]) (192x64)
//   next 4096:  Wg = bf16(gcn_w)                           (64x64)
// ---------------------------------------------------------------------------
__global__ __launch_bounds__(256) void k0_all(
    const float* __restrict__ A, const float* __restrict__ qw,
    const float* __restrict__ onw, const float* __restrict__ gw,
    __bf16* __restrict__ Apad, __bf16* __restrict__ Wbf,
    __bf16* __restrict__ onw_bf, __bf16* __restrict__ Wg)
{
    const int i = blockIdx.x * 256 + threadIdx.x;   // 0..69119
    if (i < UP_ * KP_) {
        const int u = i / KP_, v = i % KP_;
        const float val = (u < V_ && v < V_) ? A[u * V_ + v] : 0.f;
        Apad[i] = (__bf16)val;
    } else {
        const int j = i - UP_ * KP_;                // 0..22527
        if (j < 96 * C_) {
            Wbf[j] = (__bf16)qw[j];
        } else if (j < 96 * C_ + 192 * C_) {
            const int k = j - 96 * C_;              // 0..12287
            const int c = k & 63, r = k >> 6, o = r & 63, s = r >> 6;
            onw_bf[k] = (__bf16)onw[o * 192 + s * 64 + c];
        } else {
            const int k = j - (96 * C_ + 192 * C_); // 0..4095
            Wg[k] = (__bf16)gw[k];
        }
    }
}

// ---------------------------------------------------------------------------
// K1 (fused, double MFMA): per (n,t) block
//   MFMA1: h[v][c] = sum_a x[n,a,t,v] * Wg[c,a]   (A = x-gather, B = Wg)
//          -> + gcn_b -> bf16 -> hs[c][v] in LDS (don't-care pad v>=204,
//             zeroed 208..223 to stay finite; Apad cols >=204 are zero)
//   MFMA2: G[c][u] = sum_v Apad[u,v] * hs[c,v]    (A = Apad, B = hs)
//          -> g = relu(G*s1 + sh + x), float4 stores
// ---------------------------------------------------------------------------
__global__ __launch_bounds__(256) void k1_fused(
    const float* __restrict__ x, const __bf16* __restrict__ Wg,
    const float* __restrict__ gb, const __bf16* __restrict__ Apad,
    const float* __restrict__ bng, const float* __restrict__ bnb,
    const float* __restrict__ bnm, const float* __restrict__ bnv,
    float* __restrict__ g_out)
{
    __shared__ __bf16 hs[C_][232];
    const int t = blockIdx.x, n = blockIdx.y;
    const int tid = threadIdx.x;
    const int wave = tid >> 6, lane = tid & 63;
    const int l16 = lane & 15, quad = lane >> 4;

    // zero hs cols 208..223 (read by MFMA2 kc=6; multiplied by Apad zeros,
    // but must be finite)
    if (tid < 128) {
        const int c = tid >> 1, half = tid & 1;
        int* zp = (int*)&hs[c][208 + half * 8];
        zp[0] = 0; zp[1] = 0; zp[2] = 0; zp[3] = 0;
    }

    const int cB = wave * 16 + l16;          // this lane's c row (B-side)

    // ---- MFMA1 ----
    bf16x8 wfrag[2];
#pragma unroll
    for (int kc = 0; kc < 2; ++kc)
        wfrag[kc] = *(const bf16x8*)(Wg + (size_t)cB * C_ + kc * 32 + quad * 8);

    const float* xrow = x + (size_t)n * CTV_ + (size_t)t * V_;
    f32x4 acc[13];
#pragma unroll
    for (int i = 0; i < 13; ++i) acc[i] = (f32x4){0.f, 0.f, 0.f, 0.f};

#pragma unroll 1
    for (int vt = 0; vt < 13; ++vt) {
        const int v = vt * 16 + l16;
#pragma unroll
        for (int kc = 0; kc < 2; ++kc) {
            bf16x8 af;
#pragma unroll
            for (int e = 0; e < 8; ++e) af[e] = (__bf16)0.f;
            if (v < V_) {
                const float* xp = xrow + v + (size_t)(kc * 32 + quad * 8) * TV_;
#pragma unroll
                for (int e = 0; e < 8; ++e) af[e] = (__bf16)xp[(size_t)e * TV_];
            }
            acc[vt] = __builtin_amdgcn_mfma_f32_16x16x32_bf16(af, wfrag[kc], acc[vt], 0, 0, 0);
        }
    }

    // bias + pack to hs[c][v] (lane holds 4 consecutive v for fixed c = cB)
    const float biasc = gb[cB];
#pragma unroll
    for (int vt = 0; vt < 13; ++vt) {
        const int v0 = vt * 16 + quad * 4;
        bf16x4 hv;
#pragma unroll
        for (int i = 0; i < 4; ++i) hv[i] = (__bf16)(acc[vt][i] + biasc);
        *(bf16x4*)&hs[cB][v0] = hv;
    }
    __syncthreads();

    // ---- MFMA2 ----
#pragma unroll
    for (int i = 0; i < 13; ++i) acc[i] = (f32x4){0.f, 0.f, 0.f, 0.f};

    const __bf16* hrow = &hs[cB][0];
#pragma unroll 1
    for (int kc = 0; kc < 7; ++kc) {
        const bf16x8 bh = *(const bf16x8*)(hrow + kc * 32 + quad * 8);
#pragma unroll
        for (int ut = 0; ut < 13; ++ut) {
            const bf16x8 aA = *(const bf16x8*)(Apad + (size_t)(ut * 16 + l16) * KP_ + kc * 32 + quad * 8);
            acc[ut] = __builtin_amdgcn_mfma_f32_16x16x32_bf16(aA, bh, acc[ut], 0, 0, 0);
        }
    }

    // epilogue: lane holds G[cB][u0..u0+3], float4 in/out
    const float s1 = bng[cB] * rsqrtf(bnv[cB] + EPS_);
    const float sh = bnb[cB] - bnm[cB] * s1;
    const float* xres = x + (size_t)n * CTV_ + (size_t)cB * TV_ + (size_t)t * V_;
    float* gout = g_out + (size_t)n * CTV_ + (size_t)cB * TV_ + (size_t)t * V_;
#pragma unroll
    for (int ut = 0; ut < 13; ++ut) {
        const int u0 = ut * 16 + quad * 4;
        if (u0 < V_) {       // u0 == 204 only for (ut=12, quad=3) -> skip
            const float4 x4 = *(const float4*)(xres + u0);
            float4 o;
            o.x = fmaxf(acc[ut][0] * s1 + sh + x4.x, 0.f);
            o.y = fmaxf(acc[ut][1] * s1 + sh + x4.y, 0.f);
            o.z = fmaxf(acc[ut][2] * s1 + sh + x4.z, 0.f);
            o.w = fmaxf(acc[ut][3] * s1 + sh + x4.w, 0.f);
            *(float4*)(gout + u0) = o;
        }
    }
}

// ---------------------------------------------------------------------------
// K2 (MFMA): qk[(n,tv), j] = sum_c bf16(g+pe)[tv,c] * Wbf[j,c] + qb[j]
// ---------------------------------------------------------------------------
__global__ __launch_bounds__(256) void k2_mfma(
    const float* __restrict__ g_ws, const float* __restrict__ pe,
    const __bf16* __restrict__ Wbf, const float* __restrict__ qb,
    float* __restrict__ qk_ws)
{
    const int bx  = blockIdx.x;            // 0..6527
    const int n   = bx / 204;
    const int tvb = (bx % 204) * 64;
    const int wave = threadIdx.x >> 6;
    const int lane = threadIdx.x & 63;
    const int l16  = lane & 15;
    const int quad = lane >> 4;

    const int tv = tvb + wave * 16 + l16;
    const float* gp = g_ws + (size_t)n * CTV_ + tv;
    const float* pp = pe + tv;
    bf16x8 a[2];
#pragma unroll
    for (int kc = 0; kc < 2; ++kc) {
#pragma unroll
        for (int e = 0; e < 8; ++e) {
            const int c = kc * 32 + quad * 8 + e;
            a[kc][e] = (__bf16)(gp[(size_t)c * TV_] + pp[(size_t)c * TV_]);
        }
    }

    f32x4 acc[6];
#pragma unroll
    for (int jt = 0; jt < 6; ++jt) acc[jt] = (f32x4){0.f, 0.f, 0.f, 0.f};

#pragma unroll
    for (int kc = 0; kc < 2; ++kc) {
#pragma unroll
        for (int jt = 0; jt < 6; ++jt) {
            const bf16x8 b = *(const bf16x8*)(Wbf + (size_t)(jt * 16 + l16) * C_ + kc * 32 + quad * 8);
            acc[jt] = __builtin_amdgcn_mfma_f32_16x16x32_bf16(a[kc], b, acc[jt], 0, 0, 0);
        }
    }

    const int rrow = tvb + wave * 16 + quad * 4;
#pragma unroll
    for (int jt = 0; jt < 6; ++jt) {
        const int j = jt * 16 + l16;
        const float bias = qb[j];
        float* op = qk_ws + (size_t)(n * 96 + j) * TV_ + rrow;
        float4 o;
        o.x = acc[jt][0] + bias;
        o.y = acc[jt][1] + bias;
        o.z = acc[jt][2] + bias;
        o.w = acc[jt][3] + bias;
        *(float4*)op = o;
    }
}

// ---------------------------------------------------------------------------
// K3a: att partials; K3b: finalize + transpose to bf16 [n][q][s*64+t]
// ---------------------------------------------------------------------------
__global__ __launch_bounds__(64) void k3_att_part(
    const float* __restrict__ qk_ws, float* __restrict__ part)
{
    const int qcg = blockIdx.x;
    const int n = blockIdx.y;
    const int h  = blockIdx.z >> 2;
    const int wv = blockIdx.z & 3;
    const int q = threadIdx.x;
    float acc[16];
#pragma unroll
    for (int i = 0; i < 16; ++i) acc[i] = 0.f;

#pragma unroll 1
    for (int qc2 = 0; qc2 < 2; ++qc2) {
        const int qc = qcg * 2 + qc2;
        const float* Qp = qk_ws + (size_t)(n * 96 + h * 16 + qc) * TV_;
        const float* Kp = qk_ws + (size_t)(n * 96 + 48 + h * 16 + qc) * TV_;
#pragma unroll 1
        for (int vc = 0; vc < 3; ++vc) {
            const int v0 = vc * 68;
            float kr[68];
            const float* kp = Kp + (size_t)q * V_ + v0;
#pragma unroll
            for (int m = 0; m < 17; ++m) {
                float4 f = *(const float4*)(kp + m * 4);
                kr[m * 4 + 0] = f.x; kr[m * 4 + 1] = f.y;
                kr[m * 4 + 2] = f.z; kr[m * 4 + 3] = f.w;
            }
#pragma unroll 1
            for (int ti = 0; ti < 16; ++ti) {
                const int tt = wv * 16 + ti;
                const float* qp = Qp + (size_t)tt * V_ + v0;
                float a = acc[ti];
#pragma unroll
                for (int vv = 0; vv < 68; ++vv) a = fmaf(qp[vv], kr[vv], a);
                acc[ti] = a;
            }
        }
    }
    float* pp = part + ((size_t)qcg * NH_ + (size_t)(n * H_ + h)) * 4096;
#pragma unroll
    for (int ti = 0; ti < 16; ++ti) pp[(wv * 16 + ti) * 64 + q] = acc[ti];
}

__global__ __launch_bounds__(256) void k3_att_fin(
    const float* __restrict__ part, const float* __restrict__ alphas,
    const float* __restrict__ att1s, __bf16* __restrict__ att_bt)
{
    const int i = blockIdx.x * 256 + threadIdx.x;
    float s = 0.f;
#pragma unroll
    for (int p = 0; p < 8; ++p) s += part[(size_t)p * NH_ * 4096 + i];
    const int nh = i >> 12;
    const int h  = nh % H_;
    const int n  = nh / H_;
    const int tq = i & 4095;
    const int t  = tq >> 6;
    const int q  = tq & 63;
    const float val = tanhf(s * ATT_SC_) * alphas[h] + att1s[h * 4096 + tq];
    att_bt[((size_t)n * 64 + q) * 192 + h * 64 + t] = (__bf16)val;
}

// ---------------------------------------------------------------------------
// K4a (MFMA): P[np][(s*64+o)][tv] bf16 = sum_c onw_bf[(s,o)][c] * g[np][c][tv]
// ---------------------------------------------------------------------------
__global__ __launch_bounds__(256) void k4a_mfma(
    const float* __restrict__ g_chunk, const __bf16* __restrict__ onw_bf,
    __bf16* __restrict__ P)
{
    const int tvt = blockIdx.x;        // 0..203
    const int np  = blockIdx.y;        // 0..15
    const int wave = threadIdx.x >> 6;
    const int lane = threadIdx.x & 63;
    const int l16  = lane & 15;
    const int quad = lane >> 4;
    const int tv = tvt * 64 + wave * 16 + l16;

    const float* gp = g_chunk + (size_t)np * CTV_ + tv;
    bf16x8 b[2];
#pragma unroll
    for (int kc = 0; kc < 2; ++kc) {
#pragma unroll
        for (int e = 0; e < 8; ++e)
            b[kc][e] = (__bf16)gp[(size_t)(kc * 32 + quad * 8 + e) * TV_];
    }

    __bf16* Pp = P + (size_t)np * 192 * TV_ + tv;
#pragma unroll
    for (int mt = 0; mt < 12; ++mt) {
        f32x4 acc = (f32x4){0.f, 0.f, 0.f, 0.f};
#pragma unroll
        for (int kc = 0; kc < 2; ++kc) {
            const bf16x8 a = *(const bf16x8*)(onw_bf + (mt * 16 + l16) * C_ + kc * 32 + quad * 8);
            acc = __builtin_amdgcn_mfma_f32_16x16x32_bf16(a, b[kc], acc, 0, 0, 0);
        }
#pragma unroll
        for (int i = 0; i < 4; ++i)
            Pp[(size_t)(mt * 16 + quad * 4 + i) * TV_] = (__bf16)acc[i];
    }
}

// ---------------------------------------------------------------------------
// K4b (MFMA): y[q,v] per (np,o) = sum_{k=0..191} att_bt[q][k] * P[(s,o)][t,v]
// ---------------------------------------------------------------------------
__global__ __launch_bounds__(256) void k4b_mfma(
    const __bf16* __restrict__ P,
    const __bf16* __restrict__ att_bt_chunk,   // [np][q][192]
    const float* __restrict__ g_chunk,
    const float* __restrict__ onb,
    const float* __restrict__ bng, const float* __restrict__ bnb,
    const float* __restrict__ bnm, const float* __restrict__ bnv,
    float* __restrict__ out_chunk)
{
    const int o  = blockIdx.x;   // 0..63
    const int np = blockIdx.y;   // 0..15
    const int wave = threadIdx.x >> 6;
    const int lane = threadIdx.x & 63;
    const int l16  = lane & 15;
    const int quad = lane >> 4;
    const int q0 = wave * 16;

    const __bf16* ap = att_bt_chunk + ((size_t)np * 64 + q0 + l16) * 192 + quad * 8;
    bf16x8 a[6];
#pragma unroll
    for (int kk = 0; kk < 6; ++kk) a[kk] = *(const bf16x8*)(ap + kk * 32);

    const __bf16* bp[6];
#pragma unroll
    for (int kk = 0; kk < 6; ++kk)
        bp[kk] = P + ((size_t)np * 192 + (kk >> 1) * 64 + o) * TV_
                   + (size_t)((kk & 1) * 32 + quad * 8) * V_ + l16;

    f32x4 acc[13];
#pragma unroll
    for (int vt = 0; vt < 13; ++vt) acc[vt] = (f32x4){0.f, 0.f, 0.f, 0.f};

#pragma unroll
    for (int vt = 0; vt < 13; ++vt) {
#pragma unroll
        for (int kk = 0; kk < 6; ++kk) {
            bf16x8 b;
#pragma unroll
            for (int e = 0; e < 8; ++e) b[e] = bp[kk][e * V_ + vt * 16];
            acc[vt] = __builtin_amdgcn_mfma_f32_16x16x32_bf16(a[kk], b, acc[vt], 0, 0, 0);
        }
    }

    const float s1 = bng[o] * rsqrtf(bnv[o] + EPS_);
    const float sh = onb[o] * s1 + bnb[o] - bnm[o] * s1;
    const float* gp = g_chunk + (size_t)np * CTV_ + (size_t)o * TV_;
    float* zp = out_chunk + (size_t)np * CTV_ + (size_t)o * TV_;
    const int q = q0 + quad * 4;
#pragma unroll
    for (int vt = 0; vt < 13; ++vt) {
        const int v = vt * 16 + l16;
        if (v < V_) {
#pragma unroll
            for (int i = 0; i < 4; ++i) {
                float val = acc[vt][i] * s1 + sh + gp[(size_t)(q + i) * V_ + v];
                zp[(size_t)(q + i) * V_ + v] = (val > 0.f) ? val : 0.1f * val;
            }
        }
    }
}

// ---------------------------------------------------------------------------
// K5: out = leaky(bn(ff_w @ y3 + ff_b) + g), in-place on d_out
// ---------------------------------------------------------------------------
__global__ __launch_bounds__(256) void k5_ff(
    const float* __restrict__ g_ws, const float* __restrict__ fw, const float* __restrict__ fb,
    const float* __restrict__ bng, const float* __restrict__ bnb,
    const float* __restrict__ bnm, const float* __restrict__ bnv,
    float* __restrict__ io)
{
    __shared__ float ws[C_ * C_];            // 16 KB
    const int t = blockIdx.x, n = blockIdx.y;
    const int tid = threadIdx.x;
    {
        const float4* src = (const float4*)fw;
        float4* dst = (float4*)ws;
#pragma unroll
        for (int i = 0; i < 4; ++i) dst[tid + i * 256] = src[tid + i * 256];
    }
    __syncthreads();

    const int v = tid;
    if (v >= V_) return;
    float yc[C_];
    float* bp = io + (size_t)n * CTV_ + (size_t)t * V_ + v;
#pragma unroll
    for (int a = 0; a < C_; ++a) yc[a] = bp[(size_t)a * TV_];
    const float* gp = g_ws + (size_t)n * CTV_ + (size_t)t * V_ + v;
#pragma unroll 2
    for (int o = 0; o < C_; ++o) {
        float acc = fb[o];
        const float* wr = ws + o * C_;
#pragma unroll
        for (int a = 0; a < C_; ++a) acc = fmaf(wr[a], yc[a], acc);
        const float s1 = bng[o] * rsqrtf(bnv[o] + EPS_);
        float val = acc * s1 + (bnb[o] - bnm[o] * s1) + gp[(size_t)o * TV_];
        bp[(size_t)o * TV_] = (val > 0.f) ? val : 0.1f * val;
    }
}

// ---------------------------------------------------------------------------
extern "C" void kernel_launch(void* const* d_in, const int* in_sizes, int n_in,
                              void* d_out, int out_size, void* d_ws, size_t ws_size,
                              hipStream_t stream)
{
    (void)in_sizes; (void)n_in; (void)out_size; (void)ws_size;
    const float* x      = (const float*)d_in[0];
    const float* A      = (const float*)d_in[1];
    const float* gcn_w  = (const float*)d_in[2];
    const float* gcn_b  = (const float*)d_in[3];
    const float* gcn_g  = (const float*)d_in[4];
    const float* gcn_bb = (const float*)d_in[5];
    const float* gcn_m  = (const float*)d_in[6];
    const float* gcn_v  = (const float*)d_in[7];
    const float* pe     = (const float*)d_in[8];
    const float* qkv_w  = (const float*)d_in[9];
    const float* qkv_b  = (const float*)d_in[10];
    const float* alphas = (const float*)d_in[11];
    const float* att1s  = (const float*)d_in[12];
    const float* on_w   = (const float*)d_in[13];
    const float* on_b   = (const float*)d_in[14];
    const float* on_g   = (const float*)d_in[15];
    const float* on_bb  = (const float*)d_in[16];
    const float* on_m   = (const float*)d_in[17];
    const float* on_v   = (const float*)d_in[18];
    const float* ff_w   = (const float*)d_in[19];
    const float* ff_b   = (const float*)d_in[20];
    const float* ff_g   = (const float*)d_in[21];
    const float* ff_bb  = (const float*)d_in[22];
    const float* ff_m   = (const float*)d_in[23];
    const float* ff_v   = (const float*)d_in[24];
    float* out = (float*)d_out;

    float* g_ws    = (float*)d_ws;                         // 26,738,688 f
    float* qk_ws   = g_ws   + (size_t)N_ * CTV_;           // 40,108,032 f
    float* part_ws = qk_ws  + (size_t)N_ * 96 * TV_;       //  3,145,728 f
    float* att_ws  = part_ws + (size_t)8 * NH_ * 4096;     //    393,216 f
    __bf16* P_bf   = (__bf16*)qk_ws;                       // alias (qk dead after k3a)
    __bf16* Apad   = (__bf16*)part_ws;                     // alias (dead before k3a writes)
    __bf16* Wbf    = Apad + (size_t)UP_ * KP_;             // alias (dead before k3a writes)
    __bf16* Wg     = Wbf + (size_t)96 * C_;                // alias (dead before k3a writes)
    __bf16* att_bt = (__bf16*)att_ws;                      // 786 KB (bf16 transposed att)
    __bf16* onw_bf = (__bf16*)att_ws + (size_t)NH_ * 4096; // +24 KB, survives k3

    k0_all<<<dim3(270), 256, 0, stream>>>(A, qkv_w, on_w, gcn_w,
                                          Apad, Wbf, onw_bf, Wg);
    k1_fused<<<dim3(T_, N_), 256, 0, stream>>>(x, Wg, gcn_b, Apad,
                                               gcn_g, gcn_bb, gcn_m, gcn_v, g_ws);
    k2_mfma<<<dim3(6528), 256, 0, stream>>>(g_ws, pe, Wbf, qkv_b, qk_ws);
    k3_att_part<<<dim3(8, N_, 12), 64, 0, stream>>>(qk_ws, part_ws);
    k3_att_fin<<<dim3((NH_ * 4096) / 256), 256, 0, stream>>>(part_ws, alphas, att1s, att_bt);

    for (int chunk = 0; chunk < 2; ++chunk) {
        const int nb = chunk * 16;
        k4a_mfma<<<dim3(204, 16), 256, 0, stream>>>(
            g_ws + (size_t)nb * CTV_, onw_bf, P_bf);
        k4b_mfma<<<dim3(64, 16), 256, 0, stream>>>(
            P_bf, att_bt + (size_t)nb * 64 * 192, g_ws + (size_t)nb * CTV_,
            on_b, on_g, on_bb, on_m, on_v, out + (size_t)nb * CTV_);
    }
    k5_ff<<<dim3(T_, N_), 256, 0, stream>>>(g_ws, ff_w, ff_b, ff_g, ff_bb, ff_m, ff_v, out);
}